// Round 5
// baseline (335.330 us; speedup 1.0000x reference)
//
#include <hip/hip_runtime.h>

// Problem dims (fixed by setup_inputs)
#define Bb 8
#define Tt 2048
#define Hh 1024
#define Kk 256
#define Vv 256
#define Oo 1024
#define CC 64   // chunk length
#define NC 32   // chunks per batch (Tt/CC)

typedef __attribute__((ext_vector_type(8))) __bf16 bf16x8;
typedef __attribute__((ext_vector_type(4))) float f32x4;

__device__ __forceinline__ unsigned short f2b(float f) {
  unsigned u = __float_as_uint(f);
  u = (u + 0x7FFFu + ((u >> 16) & 1u)) >> 16;
  return (unsigned short)u;
}
__device__ __forceinline__ float b2f(unsigned short u) {
  return __uint_as_float(((unsigned)u) << 16);
}
__device__ __forceinline__ void gload_lds16(const unsigned short* g, unsigned short* l) {
  __builtin_amdgcn_global_load_lds(
      (const __attribute__((address_space(1))) void*)g,
      (__attribute__((address_space(3))) void*)l, 16, 0, 0);
}

// ---------------- cast f32 -> bf16 (vectorized) ----------------
__global__ __launch_bounds__(256) void cast_bf16_kernel(const float* __restrict__ in,
                                                        unsigned short* __restrict__ out,
                                                        int n4) {
  int i = blockIdx.x * 256 + threadIdx.x;
  if (i >= n4) return;
  float4 v = ((const float4*)in)[i];
  ushort4 o;
  o.x = f2b(v.x); o.y = f2b(v.y); o.z = f2b(v.z); o.w = f2b(v.w);
  ((ushort4*)out)[i] = o;
}

// ---------------- transpose + cast: W (H x N) f32 -> WT (N x H) bf16 ----------------
__global__ __launch_bounds__(256) void transpose_cast_kernel(const float* __restrict__ W,
                                                             unsigned short* __restrict__ WT,
                                                             int H, int N) {
  __shared__ float tile[32][33];
  int h0 = blockIdx.x * 32, n0 = blockIdx.y * 32;
  int tx = threadIdx.x & 31, ty = threadIdx.x >> 5;
  for (int r = ty; r < 32; r += 8)
    tile[r][tx] = W[(size_t)(h0 + r) * N + n0 + tx];
  __syncthreads();
  for (int r = ty; r < 32; r += 8)
    WT[(size_t)(n0 + r) * H + h0 + tx] = f2b(tile[tx][r]);
}

// ---------------- batched bf16 transpose: in (R x C) -> out (C x R), z = matrix idx ----
__global__ __launch_bounds__(256) void transpose_b16_kernel(
    const unsigned short* __restrict__ in, unsigned short* __restrict__ out,
    int R, int C) {
  __shared__ unsigned short tile[32][33];
  const int r0 = blockIdx.x * 32, c0 = blockIdx.y * 32;
  const size_t base = (size_t)blockIdx.z * R * C;
  const int tx = threadIdx.x & 31, ty = threadIdx.x >> 5;
  for (int rr = ty; rr < 32; rr += 8)
    tile[rr][tx] = in[base + (size_t)(r0 + rr) * C + c0 + tx];
  __syncthreads();
  for (int rr = ty; rr < 32; rr += 8)
    out[base + (size_t)(c0 + rr) * R + r0 + tx] = tile[tx][rr];
}

// ---------------- 256x256 MFMA GEMM, BK=64, 8 waves, dbuf LDS, swizzled stage -------
// C = A (MxK, bf16 row-major) * Bt^T (Bt NxK bf16 row-major)
// MODE 0: fused projection epilogue: block's n0>>8 selects {q, sigmoid->k, log2sig->g(f16), v}
// MODE 1: f32 out with bias b0p
#define BM 256
#define BN 256
#define BK 64

template <int MODE>
__global__ __launch_bounds__(512) void gemm_fused_kernel(
    const unsigned short* __restrict__ A, const unsigned short* __restrict__ Bt,
    const float* __restrict__ b0p, const float* __restrict__ b1p,
    const float* __restrict__ b2p, const float* __restrict__ b3p,
    float* __restrict__ Cf,
    unsigned short* __restrict__ O0, unsigned short* __restrict__ O1,
    unsigned short* __restrict__ O2, unsigned short* __restrict__ O3,
    int M, int N, int K) {
  // LDS: 2 bufs x (256x64) x 2 tiles x 2B = 128 KiB. Rows are 64 bf16 = 128B.
  // Content is chunk-swizzled: LDS(row, chunk) holds global chunk (chunk ^ (row&7)),
  // achieved by pre-swizzling the per-lane GLOBAL source (LDS write stays linear,
  // as global_load_lds requires). Reads apply the same XOR -> 2-way conflicts (free).
  __shared__ __align__(16) unsigned short As[2][BM * BK];
  __shared__ __align__(16) unsigned short Bs[2][BN * BK];
  const int tid = threadIdx.x;
  const int lane = tid & 63, wid = tid >> 6;       // 8 waves
  const int wm = wid >> 2, wn = wid & 3;            // 2 x 4 wave grid; wave = 128x64 out
  // XCD-aware bijective swizzle (nwg = 256, divisible by 8)
  const int lin = blockIdx.x + blockIdx.y * gridDim.x;
  const int cpx = (gridDim.x * gridDim.y) >> 3;
  const int swz = (lin & 7) * cpx + (lin >> 3);
  const int m0 = (swz / gridDim.x) * BM, n0 = (swz % gridDim.x) * BN;
  const int fr = lane & 15, fq = lane >> 4;
  // staging: per gload_lds instr a wave writes 8 rows (1024B). Lane l -> row +l>>3,
  // LDS chunk l&7; global chunk = (l&7) ^ ((l>>3)&7)  (row base multiple of 8).
  const int srl = lane >> 3;                        // row within 8-row group
  const int scs = ((lane & 7) ^ srl) * 8;           // swizzled source chunk (elements)
  const unsigned short* gaBase = A + (size_t)(m0 + srl) * K + scs;
  const unsigned short* gbBase = Bt + (size_t)(n0 + srl) * K + scs;

  f32x4 acc[8][4] = {};
  const int nt = K / BK;
#define STAGE(buf, k0)                                                         \
  {                                                                            \
    _Pragma("unroll") for (int inst = 0; inst < 4; ++inst) {                   \
      const int rb = wid * 32 + inst * 8;                                      \
      gload_lds16(gaBase + (size_t)rb * K + (k0), &As[buf][rb * BK]);          \
      gload_lds16(gbBase + (size_t)rb * K + (k0), &Bs[buf][rb * BK]);          \
    }                                                                          \
  }
  STAGE(0, 0);
  __syncthreads();
  int cur = 0;
  for (int t = 0; t < nt; ++t) {
    if (t + 1 < nt) STAGE(cur ^ 1, (t + 1) * BK);
#pragma unroll
    for (int ks = 0; ks < 2; ++ks) {
      bf16x8 bfv[4];
#pragma unroll
      for (int j = 0; j < 4; ++j) {
        const int R = wn * 64 + j * 16 + fr;
        const int ch = ((ks << 2) | fq) ^ (fr & 7);
        bfv[j] = *(const bf16x8*)&Bs[cur][R * BK + ch * 8];
      }
#pragma unroll
      for (int ih = 0; ih < 2; ++ih) {
        bf16x8 af[4];
#pragma unroll
        for (int ii = 0; ii < 4; ++ii) {
          const int R = wm * 128 + (ih * 4 + ii) * 16 + fr;
          const int ch = ((ks << 2) | fq) ^ (fr & 7);
          af[ii] = *(const bf16x8*)&As[cur][R * BK + ch * 8];
        }
#pragma unroll
        for (int ii = 0; ii < 4; ++ii)
#pragma unroll
          for (int j = 0; j < 4; ++j)
            acc[ih * 4 + ii][j] =
                __builtin_amdgcn_mfma_f32_16x16x32_bf16(af[ii], bfv[j], acc[ih * 4 + ii][j], 0, 0, 0);
      }
    }
    __syncthreads();  // drains vmcnt(0): next buffer staged & frag reads done
    cur ^= 1;
  }
  // epilogue
  if (MODE == 1) {
#pragma unroll
    for (int j = 0; j < 4; ++j) {
      const int n = n0 + wn * 64 + j * 16 + fr;
      const float bv = b0p[n];
#pragma unroll
      for (int i = 0; i < 8; ++i) {
        const int mb = m0 + wm * 128 + i * 16 + fq * 4;
#pragma unroll
        for (int r = 0; r < 4; ++r)
          Cf[(size_t)(mb + r) * N + n] = acc[i][j][r] + bv;
      }
    }
  } else {
    const int sel = n0 >> 8;  // whole block maps to one output (BN==256)
    const float* bp = sel == 0 ? b0p : sel == 1 ? b1p : sel == 2 ? b2p : b3p;
    unsigned short* Op = sel == 0 ? O0 : sel == 1 ? O1 : sel == 2 ? O2 : O3;
#pragma unroll
    for (int j = 0; j < 4; ++j) {
      const int nl = wn * 64 + j * 16 + fr;
      const float bv = bp[nl];
#pragma unroll
      for (int i = 0; i < 8; ++i) {
        const int mb = m0 + wm * 128 + i * 16 + fq * 4;
#pragma unroll
        for (int r = 0; r < 4; ++r) {
          const int m = mb + r;
          const float x = acc[i][j][r] + bv;
          if (sel == 0) {
            Op[(size_t)m * Kk + nl] = f2b(x);
          } else if (sel == 1) {
            Op[(size_t)m * Kk + nl] = f2b(1.f / (1.f + expf(-x)));
          } else if (sel == 2) {
            float e = exp2f(-x * 1.44269504f);
            float lg = -log2f(1.f + e);
            _Float16 hv = (_Float16)lg;
            unsigned short u;
            __builtin_memcpy(&u, &hv, 2);
            Op[(size_t)m * Kk + nl] = u;
          } else {  // v plain (coalesced); transposed later
            Op[(size_t)m * Vv + nl] = f2b(x);
          }
        }
      }
    }
  }
#undef STAGE
}

// ---------------- fused prep+sgemm: per (b,c) task ----------------
__global__ __launch_bounds__(256) void prep_sgemm_kernel(
    const unsigned short* __restrict__ qb, const unsigned short* __restrict__ kb,
    const unsigned short* __restrict__ lgb, const unsigned short* __restrict__ vTb,
    unsigned short* __restrict__ q2b, unsigned short* __restrict__ qab,
    unsigned short* __restrict__ kab,
    float* __restrict__ LBb, float* __restrict__ Dendb,
    unsigned short* __restrict__ Sb) {
  __shared__ __align__(16) unsigned short khs[256][72];
  const int c = blockIdx.x, b = blockIdx.y;
  const int k = threadIdx.x;
  const int task = b * NC + c;
  const size_t rowbase = ((size_t)b * Tt + (size_t)c * CC) * Kk + k;
  float Ls = 0.f;
  float LBr[4];
#pragma unroll
  for (int gq = 0; gq < 4; ++gq) {
    LBr[gq] = Ls;
#pragma unroll
    for (int tt = 0; tt < 16; ++tt) {
      int t = gq * 16 + tt;
      _Float16 hv;
      __builtin_memcpy(&hv, &lgb[rowbase + (size_t)t * Kk], 2);
      Ls += (float)hv;
    }
  }
  const float Lend = Ls;
#pragma unroll
  for (int gq = 0; gq < 4; ++gq) LBb[(size_t)task * 1024 + gq * 256 + k] = LBr[gq];
  Dendb[task * 256 + k] = exp2f(Lend);
  float L = 0.f;
#pragma unroll
  for (int gq = 0; gq < 4; ++gq) {
    const float LBc = LBr[gq];
    unsigned kw[8];
#pragma unroll
    for (int tt = 0; tt < 16; ++tt) {
      int t = gq * 16 + tt;
      size_t off = rowbase + (size_t)t * Kk;
      _Float16 hv;
      __builtin_memcpy(&hv, &lgb[off], 2);
      L += (float)hv;
      float qv = b2f(qb[off]);
      float kv = b2f(kb[off]);
      q2b[off] = f2b(qv * exp2f(L));
      qab[off] = f2b(qv * exp2f(L - LBc));
      kab[off] = f2b(kv * exp2f(LBc - L));
      unsigned short kh = f2b(kv * exp2f(Lend - L));
      if (tt & 1) kw[tt >> 1] |= ((unsigned)kh) << 16;
      else        kw[tt >> 1] = kh;
    }
    uint4 u0; u0.x = kw[0]; u0.y = kw[1]; u0.z = kw[2]; u0.w = kw[3];
    uint4 u1; u1.x = kw[4]; u1.y = kw[5]; u1.z = kw[6]; u1.w = kw[7];
    *(uint4*)&khs[k][gq * 16] = u0;
    *(uint4*)&khs[k][gq * 16 + 8] = u1;
  }
  __syncthreads();
  const int tid = threadIdx.x, lane = tid & 63, w = tid >> 6;
  const int fr = lane & 15, fq = lane >> 4, fk = fq * 8;
  const unsigned short* vt = vTb + (size_t)b * (Vv * Tt) + (size_t)c * CC;
  for (int vb4 = 0; vb4 < 4; ++vb4) {
    f32x4 acc[4][4] = {};
#pragma unroll
    for (int ks = 0; ks < 2; ++ks) {
      bf16x8 af[4], bf[4];
#pragma unroll
      for (int i = 0; i < 4; ++i)
        af[i] = *(const bf16x8*)&khs[w * 64 + i * 16 + fr][ks * 32 + fk];
#pragma unroll
      for (int j = 0; j < 4; ++j)
        bf[j] = *(const bf16x8*)(vt + (size_t)(vb4 * 64 + j * 16 + fr) * Tt + ks * 32 + fk);
#pragma unroll
      for (int i = 0; i < 4; ++i)
#pragma unroll
        for (int j = 0; j < 4; ++j)
          acc[i][j] = __builtin_amdgcn_mfma_f32_16x16x32_bf16(af[i], bf[j], acc[i][j], 0, 0, 0);
    }
#pragma unroll
    for (int i = 0; i < 4; ++i)
#pragma unroll
      for (int j = 0; j < 4; ++j)
#pragma unroll
        for (int r = 0; r < 4; ++r)
          Sb[(size_t)task * (Kk * Vv) + (size_t)(w * 64 + i * 16 + fq * 4 + r) * Vv +
             vb4 * 64 + j * 16 + fr] = f2b(acc[i][j][r]);
  }
}

// ---------------- passR: sequential chunk recombine (parallel over B,K,V) ----------------
__global__ __launch_bounds__(256) void passR_kernel(
    const unsigned short* __restrict__ Sb, const float* __restrict__ Dendb,
    unsigned short* __restrict__ S0Tb, float* __restrict__ state_out) {
  const int vt = blockIdx.x, kt = blockIdx.y, b = blockIdx.z;
  const int tid = threadIdx.x;
  const int kq = tid >> 2;
  const int vq = tid & 3;
  const int vr = tid >> 2;
  const int kqq = tid & 3;
  __shared__ __align__(16) unsigned short Ts[64][72];
  float st[16];
#pragma unroll
  for (int j = 0; j < 16; ++j) st[j] = 0.f;
  for (int c = 0; c < NC; ++c) {
    const int task = b * NC + c;
#pragma unroll
    for (int j = 0; j < 16; ++j) Ts[vq * 16 + j][kq] = f2b(st[j]);
    __syncthreads();
    {
      unsigned short* dst = S0Tb + (size_t)task * (Kk * Vv) +
                            (size_t)(vt * 64 + vr) * Kk + kt * 64 + kqq * 16;
      *(uint4*)dst = *(const uint4*)&Ts[vr][kqq * 16];
      *(uint4*)(dst + 8) = *(const uint4*)&Ts[vr][kqq * 16 + 8];
    }
    __syncthreads();
    const float d = Dendb[task * 256 + kt * 64 + kq];
    const unsigned short* sp = Sb + (size_t)task * (Kk * Vv) +
                               (size_t)(kt * 64 + kq) * Vv + vt * 64 + vq * 16;
#pragma unroll
    for (int h = 0; h < 2; ++h) {
      uint4 raw = *(const uint4*)(sp + h * 8);
      unsigned ws_[4] = {raw.x, raw.y, raw.z, raw.w};
#pragma unroll
      for (int e = 0; e < 4; ++e) {
        float lo = __uint_as_float(ws_[e] << 16);
        float hi = __uint_as_float(ws_[e] & 0xFFFF0000u);
        st[h * 8 + e * 2]     = d * st[h * 8 + e * 2] + lo;
        st[h * 8 + e * 2 + 1] = d * st[h * 8 + e * 2 + 1] + hi;
      }
    }
  }
  float* so = state_out + (size_t)(b * Kk + kt * 64 + kq) * Vv + vt * 64 + vq * 16;
#pragma unroll
  for (int j = 0; j < 16; ++j) so[j] = st[j];
}

// ---------------- passO: per (b,c): att = q2*S0 + tril(A)*v ----------------
__global__ __launch_bounds__(256) void passO_kernel(
    const unsigned short* __restrict__ qab, const unsigned short* __restrict__ kab,
    const unsigned short* __restrict__ q2b, const float* __restrict__ LBb,
    const unsigned short* __restrict__ S0Tb, const unsigned short* __restrict__ vTb,
    unsigned short* __restrict__ attb) {
  const int c = blockIdx.x, b = blockIdx.y;
  const int task = b * NC + c;
  const int tid = threadIdx.x, lane = tid & 63, w = tid >> 6;
  const int fr = lane & 15, fq = lane >> 4, fk = fq * 8;
  __shared__ float LB_s[4][256];
  __shared__ __align__(16) unsigned short A_s[64][72];
  const size_t tbase = (size_t)task * (CC * Kk);
  for (int idx = tid; idx < 1024; idx += 256) LB_s[idx >> 8][idx & 255] = LBb[(size_t)task * 1024 + idx];
  for (int idx = tid; idx < 64 * 72 / 2; idx += 256) ((unsigned*)A_s)[idx] = 0;
  __syncthreads();
  for (int p = w; p < 10; p += 4) {
    const int I = (p >= 6) ? 3 : (p >= 3) ? 2 : (p >= 1) ? 1 : 0;
    const int J = p - (I * (I + 1)) / 2;
    f32x4 acc = {0.f, 0.f, 0.f, 0.f};
#pragma unroll
    for (int ks = 0; ks < 8; ++ks) {
      const int k0 = ks * 32 + fk;
      bf16x8 af = *(const bf16x8*)(qab + tbase + (size_t)(I * 16 + fr) * Kk + k0);
      if (I != J) {
#pragma unroll
        for (int e = 0; e < 8; ++e) {
          float d = exp2f(LB_s[I][k0 + e] - LB_s[J][k0 + e]);
          af[e] = (__bf16)((float)af[e] * d);
        }
      }
      bf16x8 bf = *(const bf16x8*)(kab + tbase + (size_t)(J * 16 + fr) * Kk + k0);
      acc = __builtin_amdgcn_mfma_f32_16x16x32_bf16(af, bf, acc, 0, 0, 0);
    }
#pragma unroll
    for (int r = 0; r < 4; ++r) {
      const int ml = fq * 4 + r, nl = fr;
      bool keep = (I != J) || (nl <= ml);
      A_s[I * 16 + ml][J * 16 + nl] = keep ? f2b(acc[r]) : (unsigned short)0;
    }
  }
  __syncthreads();
  f32x4 acc2[4][4] = {};
  const unsigned short* q2t = q2b + tbase;
  const unsigned short* s0t = S0Tb + (size_t)task * (Kk * Vv);
  const unsigned short* vtp = vTb + (size_t)b * (Vv * Tt) + (size_t)c * CC;
  const int vbase = w * 64;
#pragma unroll
  for (int ks = 0; ks < 8; ++ks) {
    const int k0 = ks * 32 + fk;
    bf16x8 af[4], bf[4];
#pragma unroll
    for (int i = 0; i < 4; ++i) af[i] = *(const bf16x8*)(q2t + (size_t)(i * 16 + fr) * Kk + k0);
#pragma unroll
    for (int j = 0; j < 4; ++j) bf[j] = *(const bf16x8*)(s0t + (size_t)(vbase + j * 16 + fr) * Kk + k0);
#pragma unroll
    for (int i = 0; i < 4; ++i)
#pragma unroll
      for (int j = 0; j < 4; ++j)
        acc2[i][j] = __builtin_amdgcn_mfma_f32_16x16x32_bf16(af[i], bf[j], acc2[i][j], 0, 0, 0);
  }
#pragma unroll
  for (int ks = 0; ks < 2; ++ks) {
    const int s0 = ks * 32 + fk;
    bf16x8 af[4], bf[4];
#pragma unroll
    for (int i = 0; i < 4; ++i) af[i] = *(const bf16x8*)&A_s[i * 16 + fr][s0];
#pragma unroll
    for (int j = 0; j < 4; ++j) bf[j] = *(const bf16x8*)(vtp + (size_t)(vbase + j * 16 + fr) * Tt + s0);
#pragma unroll
    for (int i = 0; i < 4; ++i)
#pragma unroll
      for (int j = 0; j < 4; ++j)
        acc2[i][j] = __builtin_amdgcn_mfma_f32_16x16x32_bf16(af[i], bf[j], acc2[i][j], 0, 0, 0);
  }
#pragma unroll
  for (int i = 0; i < 4; ++i)
#pragma unroll
    for (int j = 0; j < 4; ++j)
#pragma unroll
      for (int r = 0; r < 4; ++r)
        attb[((size_t)b * Tt + c * CC + i * 16 + fq * 4 + r) * Vv + vbase + j * 16 + fr]
            = f2b(acc2[i][j][r]);
}

extern "C" void kernel_launch(void* const* d_in, const int* in_sizes, int n_in,
                              void* d_out, int out_size, void* d_ws, size_t ws_size,
                              hipStream_t stream) {
  const float* hs = (const float*)d_in[0];
  const float* Wq = (const float*)d_in[1];
  const float* bq = (const float*)d_in[2];
  const float* Wk = (const float*)d_in[3];
  const float* bk = (const float*)d_in[4];
  const float* Wv = (const float*)d_in[5];
  const float* bv = (const float*)d_in[6];
  const float* Wg = (const float*)d_in[7];
  const float* bg = (const float*)d_in[8];
  const float* Wo = (const float*)d_in[9];
  const float* bo = (const float*)d_in[10];

  float* out = (float*)d_out;
  float* state_out = out + (size_t)Bb * Tt * Oo;

  char* p = (char*)d_ws;
  auto alloc = [&](size_t bytes) {
    char* r = p;
    p += (bytes + 255) & ~(size_t)255;
    return r;
  };
  unsigned short* hsb   = (unsigned short*)alloc((size_t)Bb * Tt * Hh * 2);   // 32MB
  unsigned short* WallT = (unsigned short*)alloc((size_t)1024 * Hh * 2);      // 2MB
  unsigned short* WoT   = (unsigned short*)alloc((size_t)Oo * Vv * 2);
  unsigned short* qb    = (unsigned short*)alloc((size_t)Bb * Tt * Kk * 2);   // 8MB each
  unsigned short* kb    = (unsigned short*)alloc((size_t)Bb * Tt * Kk * 2);
  unsigned short* lgb   = (unsigned short*)alloc((size_t)Bb * Tt * Kk * 2);   // f16
  unsigned short* vb    = (unsigned short*)alloc((size_t)Bb * Tt * Vv * 2);
  unsigned short* vTb   = (unsigned short*)alloc((size_t)Bb * Vv * Tt * 2);
  unsigned short* attb  = (unsigned short*)alloc((size_t)Bb * Tt * Vv * 2);
  unsigned short* q2b   = (unsigned short*)alloc((size_t)Bb * Tt * Kk * 2);
  unsigned short* qab   = (unsigned short*)alloc((size_t)Bb * Tt * Kk * 2);
  unsigned short* kab   = (unsigned short*)alloc((size_t)Bb * Tt * Kk * 2);
  float*          LBb   = (float*)alloc((size_t)Bb * NC * 4 * Kk * 4);
  float*          Dendb = (float*)alloc((size_t)Bb * NC * Kk * 4);
  unsigned short* Sb    = (unsigned short*)alloc((size_t)Bb * NC * Kk * Vv * 2);  // 32MB
  unsigned short* S0Tb  = (unsigned short*)alloc((size_t)Bb * NC * Kk * Vv * 2);  // 32MB

  // 1) casts + weight transposes (concat projection weights into WallT rows)
  int n4 = Bb * Tt * Hh / 4;
  cast_bf16_kernel<<<(n4 + 255) / 256, 256, 0, stream>>>(hs, hsb, n4);
  transpose_cast_kernel<<<dim3(Hh / 32, Kk / 32), 256, 0, stream>>>(Wq, WallT + 0 * Kk * Hh, Hh, Kk);
  transpose_cast_kernel<<<dim3(Hh / 32, Kk / 32), 256, 0, stream>>>(Wk, WallT + 1 * Kk * Hh, Hh, Kk);
  transpose_cast_kernel<<<dim3(Hh / 32, Kk / 32), 256, 0, stream>>>(Wg, WallT + 2 * Kk * Hh, Hh, Kk);
  transpose_cast_kernel<<<dim3(Hh / 32, Kk / 32), 256, 0, stream>>>(Wv, WallT + 3 * Kk * Hh, Hh, Kk);
  transpose_cast_kernel<<<dim3(Vv / 32, Oo / 32), 256, 0, stream>>>(Wo, WoT, Vv, Oo);

  // 2) fused projections: one 256^2-tile GEMM, N=1024; block's n-panel selects q/k/g/v
  gemm_fused_kernel<0><<<dim3(1024 / BN, (Bb * Tt) / BM), 512, 0, stream>>>(
      hsb, WallT, bq, bk, bg, bv, nullptr, qb, kb, lgb, vb, Bb * Tt, 1024, Hh);

  // 3) vT: per-batch transpose (T x V -> V x T)
  transpose_b16_kernel<<<dim3(Tt / 32, Vv / 32, Bb), 256, 0, stream>>>(vb, vTb, Tt, Vv);

  // 4) fused prep + per-chunk state GEMM
  prep_sgemm_kernel<<<dim3(NC, Bb), 256, 0, stream>>>(qb, kb, lgb, vTb, q2b, qab, kab,
                                                      LBb, Dendb, Sb);

  // 5) sequential chunk recombine -> S0T (pre-chunk states) + final state
  passR_kernel<<<dim3(Vv / 64, Kk / 64, Bb), 256, 0, stream>>>(Sb, Dendb, S0Tb, state_out);

  // 6) outputs: att = q2.S0 + tril(A).v
  passO_kernel<<<dim3(NC, Bb), 256, 0, stream>>>(qab, kab, q2b, LBb, S0Tb, vTb, attb);

  // 7) output projection (f32 out to d_out)
  gemm_fused_kernel<1><<<dim3(Oo / BN, (Bb * Tt) / BM), 512, 0, stream>>>(
      attb, WoT, bo, nullptr, nullptr, nullptr, out, nullptr, nullptr, nullptr, nullptr,
      Bb * Tt, Oo, Vv);
}

// Round 6
// 334.908 us; speedup vs baseline: 1.0013x; 1.0013x over previous
//
#include <hip/hip_runtime.h>

// Problem dims (fixed by setup_inputs)
#define Bb 8
#define Tt 2048
#define Hh 1024
#define Kk 256
#define Vv 256
#define Oo 1024
#define CC 64   // chunk length
#define NC 32   // chunks per batch (Tt/CC)

typedef __attribute__((ext_vector_type(8))) __bf16 bf16x8;
typedef __attribute__((ext_vector_type(4))) float f32x4;

__device__ __forceinline__ unsigned short f2b(float f) {
  unsigned u = __float_as_uint(f);
  u = (u + 0x7FFFu + ((u >> 16) & 1u)) >> 16;
  return (unsigned short)u;
}
__device__ __forceinline__ float b2f(unsigned short u) {
  return __uint_as_float(((unsigned)u) << 16);
}
__device__ __forceinline__ void gload_lds16(const unsigned short* g, unsigned short* l) {
  __builtin_amdgcn_global_load_lds(
      (const __attribute__((address_space(1))) void*)g,
      (__attribute__((address_space(3))) void*)l, 16, 0, 0);
}

// ---------------- cast f32 -> bf16 (vectorized) ----------------
__global__ __launch_bounds__(256) void cast_bf16_kernel(const float* __restrict__ in,
                                                        unsigned short* __restrict__ out,
                                                        int n4) {
  int i = blockIdx.x * 256 + threadIdx.x;
  if (i >= n4) return;
  float4 v = ((const float4*)in)[i];
  ushort4 o;
  o.x = f2b(v.x); o.y = f2b(v.y); o.z = f2b(v.z); o.w = f2b(v.w);
  ((ushort4*)out)[i] = o;
}

// ---------------- transpose + cast: W (H x N) f32 -> WT (N x H) bf16 ----------------
__global__ __launch_bounds__(256) void transpose_cast_kernel(const float* __restrict__ W,
                                                             unsigned short* __restrict__ WT,
                                                             int H, int N) {
  __shared__ float tile[32][33];
  int h0 = blockIdx.x * 32, n0 = blockIdx.y * 32;
  int tx = threadIdx.x & 31, ty = threadIdx.x >> 5;
  for (int r = ty; r < 32; r += 8)
    tile[r][tx] = W[(size_t)(h0 + r) * N + n0 + tx];
  __syncthreads();
  for (int r = ty; r < 32; r += 8)
    WT[(size_t)(n0 + r) * H + h0 + tx] = f2b(tile[tx][r]);
}

// ---------------- batched bf16 transpose: in (R x C) -> out (C x R), z = matrix idx ----
__global__ __launch_bounds__(256) void transpose_b16_kernel(
    const unsigned short* __restrict__ in, unsigned short* __restrict__ out,
    int R, int C) {
  __shared__ unsigned short tile[32][33];
  const int r0 = blockIdx.x * 32, c0 = blockIdx.y * 32;
  const size_t base = (size_t)blockIdx.z * R * C;
  const int tx = threadIdx.x & 31, ty = threadIdx.x >> 5;
  for (int rr = ty; rr < 32; rr += 8)
    tile[rr][tx] = in[base + (size_t)(r0 + rr) * C + c0 + tx];
  __syncthreads();
  for (int rr = ty; rr < 32; rr += 8)
    out[base + (size_t)(c0 + rr) * R + r0 + tx] = tile[tx][rr];
}

// ---------------- 256x256 MFMA GEMM, BK=64, 8 waves, dbuf LDS, counted vmcnt -------
// C = A (MxK, bf16 row-major) * Bt^T (Bt NxK bf16 row-major)
// MODE 0: fused projection epilogue: block's n0>>8 selects {q, sigmoid->k, log2sig->g(f16), v}
// MODE 1: f32 out with bias b0p
#define BM 256
#define BN 256
#define BK 64

template <int MODE>
__global__ __launch_bounds__(512) void gemm_fused_kernel(
    const unsigned short* __restrict__ A, const unsigned short* __restrict__ Bt,
    const float* __restrict__ b0p, const float* __restrict__ b1p,
    const float* __restrict__ b2p, const float* __restrict__ b3p,
    float* __restrict__ Cf,
    unsigned short* __restrict__ O0, unsigned short* __restrict__ O1,
    unsigned short* __restrict__ O2, unsigned short* __restrict__ O3,
    int M, int N, int K) {
  // LDS: 2 bufs x (256x64) x 2 tiles x 2B = 128 KiB. Rows are 64 bf16 = 128B.
  // Content is chunk-swizzled (pre-swizzled global source, linear LDS write,
  // same XOR on reads) -> 2-way read conflicts (free).
  __shared__ __align__(16) unsigned short As[2][BM * BK];
  __shared__ __align__(16) unsigned short Bs[2][BN * BK];
  const int tid = threadIdx.x;
  const int lane = tid & 63, wid = tid >> 6;       // 8 waves
  const int wm = wid >> 2, wn = wid & 3;            // 2 x 4 wave grid; wave = 128x64 out
  // XCD-aware bijective swizzle (nwg = 256, divisible by 8)
  const int lin = blockIdx.x + blockIdx.y * gridDim.x;
  const int cpx = (gridDim.x * gridDim.y) >> 3;
  const int swz = (lin & 7) * cpx + (lin >> 3);
  const int m0 = (swz / gridDim.x) * BM, n0 = (swz % gridDim.x) * BN;
  const int fr = lane & 15, fq = lane >> 4;
  // staging: per gload_lds instr a wave writes 8 rows (1024B). Lane l -> row +l>>3,
  // LDS chunk l&7; global chunk = (l&7) ^ ((l>>3)&7)  (row base multiple of 8).
  const int srl = lane >> 3;                        // row within 8-row group
  const int scs = ((lane & 7) ^ srl) * 8;           // swizzled source chunk (elements)
  const unsigned short* gaBase = A + (size_t)(m0 + srl) * K + scs;
  const unsigned short* gbBase = Bt + (size_t)(n0 + srl) * K + scs;

  f32x4 acc[8][4] = {};
  const int nt = K / BK;  // >= 2 always (K=256 -> 4, K=1024 -> 16)
#define STAGE(buf, k0)                                                         \
  {                                                                            \
    _Pragma("unroll") for (int inst = 0; inst < 4; ++inst) {                   \
      const int rb = wid * 32 + inst * 8;                                      \
      gload_lds16(gaBase + (size_t)rb * K + (k0), &As[buf][rb * BK]);          \
      gload_lds16(gbBase + (size_t)rb * K + (k0), &Bs[buf][rb * BK]);          \
    }                                                                          \
  }
#define COMPUTE(bufc)                                                          \
  {                                                                            \
    _Pragma("unroll") for (int ks = 0; ks < 2; ++ks) {                         \
      bf16x8 bfv[4];                                                           \
      _Pragma("unroll") for (int j = 0; j < 4; ++j) {                          \
        const int R = wn * 64 + j * 16 + fr;                                   \
        const int ch = ((ks << 2) | fq) ^ (fr & 7);                            \
        bfv[j] = *(const bf16x8*)&Bs[bufc][R * BK + ch * 8];                   \
      }                                                                        \
      _Pragma("unroll") for (int ih = 0; ih < 2; ++ih) {                       \
        bf16x8 af[4];                                                          \
        _Pragma("unroll") for (int ii = 0; ii < 4; ++ii) {                     \
          const int R = wm * 128 + (ih * 4 + ii) * 16 + fr;                    \
          const int ch = ((ks << 2) | fq) ^ (fr & 7);                          \
          af[ii] = *(const bf16x8*)&As[bufc][R * BK + ch * 8];                 \
        }                                                                      \
        _Pragma("unroll") for (int ii = 0; ii < 4; ++ii)                       \
          _Pragma("unroll") for (int j = 0; j < 4; ++j)                        \
            acc[ih * 4 + ii][j] = __builtin_amdgcn_mfma_f32_16x16x32_bf16(     \
                af[ii], bfv[j], acc[ih * 4 + ii][j], 0, 0, 0);                 \
      }                                                                        \
    }                                                                          \
  }
  // prologue: stage tile 0 into buf 0 (no wait; t=0's counted wait covers it)
  STAGE(0, 0);
  int cur = 0;
  for (int t = 0; t < nt - 1; ++t) {
    STAGE(cur ^ 1, (t + 1) * BK);  // 8 more loads in flight (not drained below)
    // wait only the previous 8 loads (current buffer), then raw barrier:
    // the 8 just-issued loads stay in flight across the barrier (T4).
    asm volatile("s_waitcnt vmcnt(8)\n\ts_barrier" ::: "memory");
    COMPUTE(cur);
    // all waves done reading buf[cur] (ds_reads consumed by MFMAs above);
    // raw barrier WITHOUT vmcnt drain so prefetch stays outstanding.
    asm volatile("s_barrier" ::: "memory");
    cur ^= 1;
  }
  // last tile: its loads are the only outstanding ones
  asm volatile("s_waitcnt vmcnt(0)\n\ts_barrier" ::: "memory");
  COMPUTE(cur);
  // epilogue
  if (MODE == 1) {
#pragma unroll
    for (int j = 0; j < 4; ++j) {
      const int n = n0 + wn * 64 + j * 16 + fr;
      const float bv = b0p[n];
#pragma unroll
      for (int i = 0; i < 8; ++i) {
        const int mb = m0 + wm * 128 + i * 16 + fq * 4;
#pragma unroll
        for (int r = 0; r < 4; ++r)
          Cf[(size_t)(mb + r) * N + n] = acc[i][j][r] + bv;
      }
    }
  } else {
    const int sel = n0 >> 8;  // whole block maps to one output (BN==256)
    const float* bp = sel == 0 ? b0p : sel == 1 ? b1p : sel == 2 ? b2p : b3p;
    unsigned short* Op = sel == 0 ? O0 : sel == 1 ? O1 : sel == 2 ? O2 : O3;
#pragma unroll
    for (int j = 0; j < 4; ++j) {
      const int nl = wn * 64 + j * 16 + fr;
      const float bv = bp[nl];
#pragma unroll
      for (int i = 0; i < 8; ++i) {
        const int mb = m0 + wm * 128 + i * 16 + fq * 4;
#pragma unroll
        for (int r = 0; r < 4; ++r) {
          const int m = mb + r;
          const float x = acc[i][j][r] + bv;
          if (sel == 0) {
            Op[(size_t)m * Kk + nl] = f2b(x);
          } else if (sel == 1) {
            Op[(size_t)m * Kk + nl] = f2b(1.f / (1.f + expf(-x)));
          } else if (sel == 2) {
            float e = exp2f(-x * 1.44269504f);
            float lg = -log2f(1.f + e);
            _Float16 hv = (_Float16)lg;
            unsigned short u;
            __builtin_memcpy(&u, &hv, 2);
            Op[(size_t)m * Kk + nl] = u;
          } else {  // v plain (coalesced); transposed later
            Op[(size_t)m * Vv + nl] = f2b(x);
          }
        }
      }
    }
  }
#undef STAGE
#undef COMPUTE
}

// ---------------- fused prep+sgemm: per (b,c) task ----------------
__global__ __launch_bounds__(256) void prep_sgemm_kernel(
    const unsigned short* __restrict__ qb, const unsigned short* __restrict__ kb,
    const unsigned short* __restrict__ lgb, const unsigned short* __restrict__ vTb,
    unsigned short* __restrict__ q2b, unsigned short* __restrict__ qab,
    unsigned short* __restrict__ kab,
    float* __restrict__ LBb, float* __restrict__ Dendb,
    unsigned short* __restrict__ Sb) {
  __shared__ __align__(16) unsigned short khs[256][72];
  const int c = blockIdx.x, b = blockIdx.y;
  const int k = threadIdx.x;
  const int task = b * NC + c;
  const size_t rowbase = ((size_t)b * Tt + (size_t)c * CC) * Kk + k;
  float Ls = 0.f;
  float LBr[4];
#pragma unroll
  for (int gq = 0; gq < 4; ++gq) {
    LBr[gq] = Ls;
#pragma unroll
    for (int tt = 0; tt < 16; ++tt) {
      int t = gq * 16 + tt;
      _Float16 hv;
      __builtin_memcpy(&hv, &lgb[rowbase + (size_t)t * Kk], 2);
      Ls += (float)hv;
    }
  }
  const float Lend = Ls;
#pragma unroll
  for (int gq = 0; gq < 4; ++gq) LBb[(size_t)task * 1024 + gq * 256 + k] = LBr[gq];
  Dendb[task * 256 + k] = exp2f(Lend);
  float L = 0.f;
#pragma unroll
  for (int gq = 0; gq < 4; ++gq) {
    const float LBc = LBr[gq];
    unsigned kw[8];
#pragma unroll
    for (int tt = 0; tt < 16; ++tt) {
      int t = gq * 16 + tt;
      size_t off = rowbase + (size_t)t * Kk;
      _Float16 hv;
      __builtin_memcpy(&hv, &lgb[off], 2);
      L += (float)hv;
      float qv = b2f(qb[off]);
      float kv = b2f(kb[off]);
      q2b[off] = f2b(qv * exp2f(L));
      qab[off] = f2b(qv * exp2f(L - LBc));
      kab[off] = f2b(kv * exp2f(LBc - L));
      unsigned short kh = f2b(kv * exp2f(Lend - L));
      if (tt & 1) kw[tt >> 1] |= ((unsigned)kh) << 16;
      else        kw[tt >> 1] = kh;
    }
    uint4 u0; u0.x = kw[0]; u0.y = kw[1]; u0.z = kw[2]; u0.w = kw[3];
    uint4 u1; u1.x = kw[4]; u1.y = kw[5]; u1.z = kw[6]; u1.w = kw[7];
    *(uint4*)&khs[k][gq * 16] = u0;
    *(uint4*)&khs[k][gq * 16 + 8] = u1;
  }
  __syncthreads();
  const int tid = threadIdx.x, lane = tid & 63, w = tid >> 6;
  const int fr = lane & 15, fq = lane >> 4, fk = fq * 8;
  const unsigned short* vt = vTb + (size_t)b * (Vv * Tt) + (size_t)c * CC;
  for (int vb4 = 0; vb4 < 4; ++vb4) {
    f32x4 acc[4][4] = {};
#pragma unroll
    for (int ks = 0; ks < 2; ++ks) {
      bf16x8 af[4], bf[4];
#pragma unroll
      for (int i = 0; i < 4; ++i)
        af[i] = *(const bf16x8*)&khs[w * 64 + i * 16 + fr][ks * 32 + fk];
#pragma unroll
      for (int j = 0; j < 4; ++j)
        bf[j] = *(const bf16x8*)(vt + (size_t)(vb4 * 64 + j * 16 + fr) * Tt + ks * 32 + fk);
#pragma unroll
      for (int i = 0; i < 4; ++i)
#pragma unroll
        for (int j = 0; j < 4; ++j)
          acc[i][j] = __builtin_amdgcn_mfma_f32_16x16x32_bf16(af[i], bf[j], acc[i][j], 0, 0, 0);
    }
#pragma unroll
    for (int i = 0; i < 4; ++i)
#pragma unroll
      for (int j = 0; j < 4; ++j)
#pragma unroll
        for (int r = 0; r < 4; ++r)
          Sb[(size_t)task * (Kk * Vv) + (size_t)(w * 64 + i * 16 + fq * 4 + r) * Vv +
             vb4 * 64 + j * 16 + fr] = f2b(acc[i][j][r]);
  }
}

// ---------------- passR: sequential chunk recombine (parallel over B,K,V) ----------------
__global__ __launch_bounds__(256) void passR_kernel(
    const unsigned short* __restrict__ Sb, const float* __restrict__ Dendb,
    unsigned short* __restrict__ S0Tb, float* __restrict__ state_out) {
  const int vt = blockIdx.x, kt = blockIdx.y, b = blockIdx.z;
  const int tid = threadIdx.x;
  const int kq = tid >> 2;
  const int vq = tid & 3;
  const int vr = tid >> 2;
  const int kqq = tid & 3;
  __shared__ __align__(16) unsigned short Ts[64][72];
  float st[16];
#pragma unroll
  for (int j = 0; j < 16; ++j) st[j] = 0.f;
  for (int c = 0; c < NC; ++c) {
    const int task = b * NC + c;
#pragma unroll
    for (int j = 0; j < 16; ++j) Ts[vq * 16 + j][kq] = f2b(st[j]);
    __syncthreads();
    {
      unsigned short* dst = S0Tb + (size_t)task * (Kk * Vv) +
                            (size_t)(vt * 64 + vr) * Kk + kt * 64 + kqq * 16;
      *(uint4*)dst = *(const uint4*)&Ts[vr][kqq * 16];
      *(uint4*)(dst + 8) = *(const uint4*)&Ts[vr][kqq * 16 + 8];
    }
    __syncthreads();
    const float d = Dendb[task * 256 + kt * 64 + kq];
    const unsigned short* sp = Sb + (size_t)task * (Kk * Vv) +
                               (size_t)(kt * 64 + kq) * Vv + vt * 64 + vq * 16;
#pragma unroll
    for (int h = 0; h < 2; ++h) {
      uint4 raw = *(const uint4*)(sp + h * 8);
      unsigned ws_[4] = {raw.x, raw.y, raw.z, raw.w};
#pragma unroll
      for (int e = 0; e < 4; ++e) {
        float lo = __uint_as_float(ws_[e] << 16);
        float hi = __uint_as_float(ws_[e] & 0xFFFF0000u);
        st[h * 8 + e * 2]     = d * st[h * 8 + e * 2] + lo;
        st[h * 8 + e * 2 + 1] = d * st[h * 8 + e * 2 + 1] + hi;
      }
    }
  }
  float* so = state_out + (size_t)(b * Kk + kt * 64 + kq) * Vv + vt * 64 + vq * 16;
#pragma unroll
  for (int j = 0; j < 16; ++j) so[j] = st[j];
}

// ---------------- passO: per (b,c): att = q2*S0 + tril(A)*v ----------------
__global__ __launch_bounds__(256) void passO_kernel(
    const unsigned short* __restrict__ qab, const unsigned short* __restrict__ kab,
    const unsigned short* __restrict__ q2b, const float* __restrict__ LBb,
    const unsigned short* __restrict__ S0Tb, const unsigned short* __restrict__ vTb,
    unsigned short* __restrict__ attb) {
  const int c = blockIdx.x, b = blockIdx.y;
  const int task = b * NC + c;
  const int tid = threadIdx.x, lane = tid & 63, w = tid >> 6;
  const int fr = lane & 15, fq = lane >> 4, fk = fq * 8;
  __shared__ float LB_s[4][256];
  __shared__ __align__(16) unsigned short A_s[64][72];
  const size_t tbase = (size_t)task * (CC * Kk);
  for (int idx = tid; idx < 1024; idx += 256) LB_s[idx >> 8][idx & 255] = LBb[(size_t)task * 1024 + idx];
  for (int idx = tid; idx < 64 * 72 / 2; idx += 256) ((unsigned*)A_s)[idx] = 0;
  __syncthreads();
  for (int p = w; p < 10; p += 4) {
    const int I = (p >= 6) ? 3 : (p >= 3) ? 2 : (p >= 1) ? 1 : 0;
    const int J = p - (I * (I + 1)) / 2;
    f32x4 acc = {0.f, 0.f, 0.f, 0.f};
#pragma unroll
    for (int ks = 0; ks < 8; ++ks) {
      const int k0 = ks * 32 + fk;
      bf16x8 af = *(const bf16x8*)(qab + tbase + (size_t)(I * 16 + fr) * Kk + k0);
      if (I != J) {
#pragma unroll
        for (int e = 0; e < 8; ++e) {
          float d = exp2f(LB_s[I][k0 + e] - LB_s[J][k0 + e]);
          af[e] = (__bf16)((float)af[e] * d);
        }
      }
      bf16x8 bf = *(const bf16x8*)(kab + tbase + (size_t)(J * 16 + fr) * Kk + k0);
      acc = __builtin_amdgcn_mfma_f32_16x16x32_bf16(af, bf, acc, 0, 0, 0);
    }
#pragma unroll
    for (int r = 0; r < 4; ++r) {
      const int ml = fq * 4 + r, nl = fr;
      bool keep = (I != J) || (nl <= ml);
      A_s[I * 16 + ml][J * 16 + nl] = keep ? f2b(acc[r]) : (unsigned short)0;
    }
  }
  __syncthreads();
  f32x4 acc2[4][4] = {};
  const unsigned short* q2t = q2b + tbase;
  const unsigned short* s0t = S0Tb + (size_t)task * (Kk * Vv);
  const unsigned short* vtp = vTb + (size_t)b * (Vv * Tt) + (size_t)c * CC;
  const int vbase = w * 64;
#pragma unroll
  for (int ks = 0; ks < 8; ++ks) {
    const int k0 = ks * 32 + fk;
    bf16x8 af[4], bf[4];
#pragma unroll
    for (int i = 0; i < 4; ++i) af[i] = *(const bf16x8*)(q2t + (size_t)(i * 16 + fr) * Kk + k0);
#pragma unroll
    for (int j = 0; j < 4; ++j) bf[j] = *(const bf16x8*)(s0t + (size_t)(vbase + j * 16 + fr) * Kk + k0);
#pragma unroll
    for (int i = 0; i < 4; ++i)
#pragma unroll
      for (int j = 0; j < 4; ++j)
        acc2[i][j] = __builtin_amdgcn_mfma_f32_16x16x32_bf16(af[i], bf[j], acc2[i][j], 0, 0, 0);
  }
#pragma unroll
  for (int ks = 0; ks < 2; ++ks) {
    const int s0 = ks * 32 + fk;
    bf16x8 af[4], bf[4];
#pragma unroll
    for (int i = 0; i < 4; ++i) af[i] = *(const bf16x8*)&A_s[i * 16 + fr][s0];
#pragma unroll
    for (int j = 0; j < 4; ++j) bf[j] = *(const bf16x8*)(vtp + (size_t)(vbase + j * 16 + fr) * Tt + s0);
#pragma unroll
    for (int i = 0; i < 4; ++i)
#pragma unroll
      for (int j = 0; j < 4; ++j)
        acc2[i][j] = __builtin_amdgcn_mfma_f32_16x16x32_bf16(af[i], bf[j], acc2[i][j], 0, 0, 0);
  }
#pragma unroll
  for (int i = 0; i < 4; ++i)
#pragma unroll
    for (int j = 0; j < 4; ++j)
#pragma unroll
      for (int r = 0; r < 4; ++r)
        attb[((size_t)b * Tt + c * CC + i * 16 + fq * 4 + r) * Vv + vbase + j * 16 + fr]
            = f2b(acc2[i][j][r]);
}

extern "C" void kernel_launch(void* const* d_in, const int* in_sizes, int n_in,
                              void* d_out, int out_size, void* d_ws, size_t ws_size,
                              hipStream_t stream) {
  const float* hs = (const float*)d_in[0];
  const float* Wq = (const float*)d_in[1];
  const float* bq = (const float*)d_in[2];
  const float* Wk = (const float*)d_in[3];
  const float* bk = (const float*)d_in[4];
  const float* Wv = (const float*)d_in[5];
  const float* bv = (const float*)d_in[6];
  const float* Wg = (const float*)d_in[7];
  const float* bg = (const float*)d_in[8];
  const float* Wo = (const float*)d_in[9];
  const float* bo = (const float*)d_in[10];

  float* out = (float*)d_out;
  float* state_out = out + (size_t)Bb * Tt * Oo;

  char* p = (char*)d_ws;
  auto alloc = [&](size_t bytes) {
    char* r = p;
    p += (bytes + 255) & ~(size_t)255;
    return r;
  };
  unsigned short* hsb   = (unsigned short*)alloc((size_t)Bb * Tt * Hh * 2);   // 32MB
  unsigned short* WallT = (unsigned short*)alloc((size_t)1024 * Hh * 2);      // 2MB
  unsigned short* WoT   = (unsigned short*)alloc((size_t)Oo * Vv * 2);
  unsigned short* qb    = (unsigned short*)alloc((size_t)Bb * Tt * Kk * 2);   // 8MB each
  unsigned short* kb    = (unsigned short*)alloc((size_t)Bb * Tt * Kk * 2);
  unsigned short* lgb   = (unsigned short*)alloc((size_t)Bb * Tt * Kk * 2);   // f16
  unsigned short* vb    = (unsigned short*)alloc((size_t)Bb * Tt * Vv * 2);
  unsigned short* vTb   = (unsigned short*)alloc((size_t)Bb * Vv * Tt * 2);
  unsigned short* attb  = (unsigned short*)alloc((size_t)Bb * Tt * Vv * 2);
  unsigned short* q2b   = (unsigned short*)alloc((size_t)Bb * Tt * Kk * 2);
  unsigned short* qab   = (unsigned short*)alloc((size_t)Bb * Tt * Kk * 2);
  unsigned short* kab   = (unsigned short*)alloc((size_t)Bb * Tt * Kk * 2);
  float*          LBb   = (float*)alloc((size_t)Bb * NC * 4 * Kk * 4);
  float*          Dendb = (float*)alloc((size_t)Bb * NC * Kk * 4);
  unsigned short* Sb    = (unsigned short*)alloc((size_t)Bb * NC * Kk * Vv * 2);  // 32MB
  unsigned short* S0Tb  = (unsigned short*)alloc((size_t)Bb * NC * Kk * Vv * 2);  // 32MB

  // 1) casts + weight transposes (concat projection weights into WallT rows)
  int n4 = Bb * Tt * Hh / 4;
  cast_bf16_kernel<<<(n4 + 255) / 256, 256, 0, stream>>>(hs, hsb, n4);
  transpose_cast_kernel<<<dim3(Hh / 32, Kk / 32), 256, 0, stream>>>(Wq, WallT + 0 * Kk * Hh, Hh, Kk);
  transpose_cast_kernel<<<dim3(Hh / 32, Kk / 32), 256, 0, stream>>>(Wk, WallT + 1 * Kk * Hh, Hh, Kk);
  transpose_cast_kernel<<<dim3(Hh / 32, Kk / 32), 256, 0, stream>>>(Wg, WallT + 2 * Kk * Hh, Hh, Kk);
  transpose_cast_kernel<<<dim3(Hh / 32, Kk / 32), 256, 0, stream>>>(Wv, WallT + 3 * Kk * Hh, Hh, Kk);
  transpose_cast_kernel<<<dim3(Vv / 32, Oo / 32), 256, 0, stream>>>(Wo, WoT, Vv, Oo);

  // 2) fused projections: one 256^2-tile GEMM, N=1024; block's n-panel selects q/k/g/v
  gemm_fused_kernel<0><<<dim3(1024 / BN, (Bb * Tt) / BM), 512, 0, stream>>>(
      hsb, WallT, bq, bk, bg, bv, nullptr, qb, kb, lgb, vb, Bb * Tt, 1024, Hh);

  // 3) vT: per-batch transpose (T x V -> V x T)
  transpose_b16_kernel<<<dim3(Tt / 32, Vv / 32, Bb), 256, 0, stream>>>(vb, vTb, Tt, Vv);

  // 4) fused prep + per-chunk state GEMM
  prep_sgemm_kernel<<<dim3(NC, Bb), 256, 0, stream>>>(qb, kb, lgb, vTb, q2b, qab, kab,
                                                      LBb, Dendb, Sb);

  // 5) sequential chunk recombine -> S0T (pre-chunk states) + final state
  passR_kernel<<<dim3(Vv / 64, Kk / 64, Bb), 256, 0, stream>>>(Sb, Dendb, S0Tb, state_out);

  // 6) outputs: att = q2.S0 + tril(A).v
  passO_kernel<<<dim3(NC, Bb), 256, 0, stream>>>(qab, kab, q2b, LBb, S0Tb, vTb, attb);

  // 7) output projection (f32 out to d_out)
  gemm_fused_kernel<1><<<dim3(Oo / BN, (Bb * Tt) / BM), 512, 0, stream>>>(
      attb, WoT, bo, nullptr, nullptr, nullptr, out, nullptr, nullptr, nullptr, nullptr,
      Bb * Tt, Oo, Vv);
}

// Round 7
// 282.873 us; speedup vs baseline: 1.1854x; 1.1840x over previous
//
#include <hip/hip_runtime.h>

// Problem dims (fixed by setup_inputs)
#define Bb 8
#define Tt 2048
#define Hh 1024
#define Kk 256
#define Vv 256
#define Oo 1024
#define CC 64   // chunk length
#define NC 32   // chunks per batch (Tt/CC)

typedef __attribute__((ext_vector_type(8))) __bf16 bf16x8;
typedef __attribute__((ext_vector_type(4))) float f32x4;

__device__ __forceinline__ unsigned short f2b(float f) {
  unsigned u = __float_as_uint(f);
  u = (u + 0x7FFFu + ((u >> 16) & 1u)) >> 16;
  return (unsigned short)u;
}
__device__ __forceinline__ float b2f(unsigned short u) {
  return __uint_as_float(((unsigned)u) << 16);
}
__device__ __forceinline__ void gload_lds16(const unsigned short* g, unsigned short* l) {
  __builtin_amdgcn_global_load_lds(
      (const __attribute__((address_space(1))) void*)g,
      (__attribute__((address_space(3))) void*)l, 16, 0, 0);
}

// ---------------- cast f32 -> bf16 (vectorized) ----------------
__global__ __launch_bounds__(256) void cast_bf16_kernel(const float* __restrict__ in,
                                                        unsigned short* __restrict__ out,
                                                        int n4) {
  int i = blockIdx.x * 256 + threadIdx.x;
  if (i >= n4) return;
  float4 v = ((const float4*)in)[i];
  ushort4 o;
  o.x = f2b(v.x); o.y = f2b(v.y); o.z = f2b(v.z); o.w = f2b(v.w);
  ((ushort4*)out)[i] = o;
}

// ---------------- transpose + cast: W (H x N) f32 -> WT (N x H) bf16 ----------------
__global__ __launch_bounds__(256) void transpose_cast_kernel(const float* __restrict__ W,
                                                             unsigned short* __restrict__ WT,
                                                             int H, int N) {
  __shared__ float tile[32][33];
  int h0 = blockIdx.x * 32, n0 = blockIdx.y * 32;
  int tx = threadIdx.x & 31, ty = threadIdx.x >> 5;
  for (int r = ty; r < 32; r += 8)
    tile[r][tx] = W[(size_t)(h0 + r) * N + n0 + tx];
  __syncthreads();
  for (int r = ty; r < 32; r += 8)
    WT[(size_t)(n0 + r) * H + h0 + tx] = f2b(tile[tx][r]);
}

// ---------------- batched bf16 transpose: in (R x C) -> out (C x R), z = matrix idx ----
__global__ __launch_bounds__(256) void transpose_b16_kernel(
    const unsigned short* __restrict__ in, unsigned short* __restrict__ out,
    int R, int C) {
  __shared__ unsigned short tile[32][33];
  const int r0 = blockIdx.x * 32, c0 = blockIdx.y * 32;
  const size_t base = (size_t)blockIdx.z * R * C;
  const int tx = threadIdx.x & 31, ty = threadIdx.x >> 5;
  for (int rr = ty; rr < 32; rr += 8)
    tile[rr][tx] = in[base + (size_t)(r0 + rr) * C + c0 + tx];
  __syncthreads();
  for (int rr = ty; rr < 32; rr += 8)
    out[base + (size_t)(c0 + rr) * R + r0 + tx] = tile[tx][rr];
}

// ---------------- 128x128 MFMA GEMM, BK=64, 4 waves, m97 discipline, swizzled LDS ----
// C = A (MxK, bf16 row-major) * Bt^T (Bt NxK bf16 row-major)
// MODE 0: fused projection epilogue: block's n0>>8 selects {q, sigmoid->k, log2sig->g(f16), v}
// MODE 1: f32 out with bias b0p
#define BM 128
#define BN 128
#define BK 64

template <int MODE>
__global__ __launch_bounds__(256) void gemm_fused_kernel(
    const unsigned short* __restrict__ A, const unsigned short* __restrict__ Bt,
    const float* __restrict__ b0p, const float* __restrict__ b1p,
    const float* __restrict__ b2p, const float* __restrict__ b3p,
    float* __restrict__ Cf,
    unsigned short* __restrict__ O0, unsigned short* __restrict__ O1,
    unsigned short* __restrict__ O2, unsigned short* __restrict__ O3,
    int M, int N, int K) {
  // LDS: (128x64)x2 tiles x2B = 32 KiB -> 4-5 blocks/CU co-resident (TLP hides drain).
  // Rows are 128B; content chunk-swizzled (pre-swizzled global source, linear LDS
  // write as global_load_lds requires, same XOR on reads) -> conflict-free ds_read_b128.
  __shared__ __align__(16) unsigned short As[BM * BK];
  __shared__ __align__(16) unsigned short Bs[BN * BK];
  const int tid = threadIdx.x;
  const int lane = tid & 63, wid = tid >> 6;        // 4 waves
  const int wm = wid >> 1, wn = wid & 1;            // 2x2 wave grid; wave = 64x64 out
  // XCD-aware bijective swizzle (nwg = 1024, divisible by 8)
  const int lin = blockIdx.x + blockIdx.y * gridDim.x;
  const int cpx = (gridDim.x * gridDim.y) >> 3;
  const int swz = (lin & 7) * cpx + (lin >> 3);
  const int m0 = (swz / gridDim.x) * BM, n0 = (swz % gridDim.x) * BN;
  const int fr = lane & 15, fq = lane >> 4;
  // staging: per gload_lds a wave writes 8 rows x 128B (1 KiB). Lane l -> row +(l>>3),
  // LDS 16B-chunk (l&7); global source chunk = (l&7) ^ (l>>3)  [row base % 8 == 0].
  const int srl = lane >> 3;
  const int scs = ((lane & 7) ^ srl) * 8;
  const unsigned short* gaBase = A + (size_t)(m0 + srl) * K + scs;
  const unsigned short* gbBase = Bt + (size_t)(n0 + srl) * K + scs;

  f32x4 acc[4][4] = {};
  const int nt = K / BK;
  for (int t = 0; t < nt; ++t) {
    const int k0 = t * BK;
    __syncthreads();  // previous iter's LDS reads done
#pragma unroll
    for (int inst = 0; inst < 4; ++inst) {
      const int rb = wid * 32 + inst * 8;
      gload_lds16(gaBase + (size_t)rb * K + k0, &As[rb * BK]);
      gload_lds16(gbBase + (size_t)rb * K + k0, &Bs[rb * BK]);
    }
    __syncthreads();  // staged data visible (vmcnt0 drain; hidden by co-resident blocks)
#pragma unroll
    for (int ks = 0; ks < 2; ++ks) {
      bf16x8 af[4], bfv[4];
#pragma unroll
      for (int j = 0; j < 4; ++j) {
        const int R = wn * 64 + j * 16 + fr;
        const int ch = ((ks << 2) | fq) ^ (fr & 7);
        bfv[j] = *(const bf16x8*)&Bs[R * BK + ch * 8];
      }
#pragma unroll
      for (int i = 0; i < 4; ++i) {
        const int R = wm * 64 + i * 16 + fr;
        const int ch = ((ks << 2) | fq) ^ (fr & 7);
        af[i] = *(const bf16x8*)&As[R * BK + ch * 8];
      }
#pragma unroll
      for (int i = 0; i < 4; ++i)
#pragma unroll
        for (int j = 0; j < 4; ++j)
          acc[i][j] = __builtin_amdgcn_mfma_f32_16x16x32_bf16(af[i], bfv[j], acc[i][j], 0, 0, 0);
    }
  }
  // epilogue
  if (MODE == 1) {
#pragma unroll
    for (int j = 0; j < 4; ++j) {
      const int n = n0 + wn * 64 + j * 16 + fr;
      const float bv = b0p[n];
#pragma unroll
      for (int i = 0; i < 4; ++i) {
        const int mb = m0 + wm * 64 + i * 16 + fq * 4;
#pragma unroll
        for (int r = 0; r < 4; ++r)
          Cf[(size_t)(mb + r) * N + n] = acc[i][j][r] + bv;
      }
    }
  } else {
    const int sel = n0 >> 8;  // n-range [n0,n0+128) never straddles a 256-panel
    const float* bp = sel == 0 ? b0p : sel == 1 ? b1p : sel == 2 ? b2p : b3p;
    unsigned short* Op = sel == 0 ? O0 : sel == 1 ? O1 : sel == 2 ? O2 : O3;
#pragma unroll
    for (int j = 0; j < 4; ++j) {
      const int nl = (n0 + wn * 64 + j * 16 + fr) & 255;
      const float bv = bp[nl];
#pragma unroll
      for (int i = 0; i < 4; ++i) {
        const int mb = m0 + wm * 64 + i * 16 + fq * 4;
#pragma unroll
        for (int r = 0; r < 4; ++r) {
          const int m = mb + r;
          const float x = acc[i][j][r] + bv;
          if (sel == 0) {
            Op[(size_t)m * Kk + nl] = f2b(x);
          } else if (sel == 1) {
            Op[(size_t)m * Kk + nl] = f2b(1.f / (1.f + expf(-x)));
          } else if (sel == 2) {
            float e = exp2f(-x * 1.44269504f);
            float lg = -log2f(1.f + e);
            _Float16 hv = (_Float16)lg;
            unsigned short u;
            __builtin_memcpy(&u, &hv, 2);
            Op[(size_t)m * Kk + nl] = u;
          } else {  // v plain (coalesced); transposed later
            Op[(size_t)m * Vv + nl] = f2b(x);
          }
        }
      }
    }
  }
}

// ---------------- fused prep+sgemm: per (b,c) task ----------------
__global__ __launch_bounds__(256) void prep_sgemm_kernel(
    const unsigned short* __restrict__ qb, const unsigned short* __restrict__ kb,
    const unsigned short* __restrict__ lgb, const unsigned short* __restrict__ vTb,
    unsigned short* __restrict__ q2b, unsigned short* __restrict__ qab,
    unsigned short* __restrict__ kab,
    float* __restrict__ LBb, float* __restrict__ Dendb,
    unsigned short* __restrict__ Sb) {
  __shared__ __align__(16) unsigned short khs[256][72];
  const int c = blockIdx.x, b = blockIdx.y;
  const int k = threadIdx.x;
  const int task = b * NC + c;
  const size_t rowbase = ((size_t)b * Tt + (size_t)c * CC) * Kk + k;
  float Ls = 0.f;
  float LBr[4];
#pragma unroll
  for (int gq = 0; gq < 4; ++gq) {
    LBr[gq] = Ls;
#pragma unroll
    for (int tt = 0; tt < 16; ++tt) {
      int t = gq * 16 + tt;
      _Float16 hv;
      __builtin_memcpy(&hv, &lgb[rowbase + (size_t)t * Kk], 2);
      Ls += (float)hv;
    }
  }
  const float Lend = Ls;
#pragma unroll
  for (int gq = 0; gq < 4; ++gq) LBb[(size_t)task * 1024 + gq * 256 + k] = LBr[gq];
  Dendb[task * 256 + k] = exp2f(Lend);
  float L = 0.f;
#pragma unroll
  for (int gq = 0; gq < 4; ++gq) {
    const float LBc = LBr[gq];
    unsigned kw[8];
#pragma unroll
    for (int tt = 0; tt < 16; ++tt) {
      int t = gq * 16 + tt;
      size_t off = rowbase + (size_t)t * Kk;
      _Float16 hv;
      __builtin_memcpy(&hv, &lgb[off], 2);
      L += (float)hv;
      float qv = b2f(qb[off]);
      float kv = b2f(kb[off]);
      q2b[off] = f2b(qv * exp2f(L));
      qab[off] = f2b(qv * exp2f(L - LBc));
      kab[off] = f2b(kv * exp2f(LBc - L));
      unsigned short kh = f2b(kv * exp2f(Lend - L));
      if (tt & 1) kw[tt >> 1] |= ((unsigned)kh) << 16;
      else        kw[tt >> 1] = kh;
    }
    uint4 u0; u0.x = kw[0]; u0.y = kw[1]; u0.z = kw[2]; u0.w = kw[3];
    uint4 u1; u1.x = kw[4]; u1.y = kw[5]; u1.z = kw[6]; u1.w = kw[7];
    *(uint4*)&khs[k][gq * 16] = u0;
    *(uint4*)&khs[k][gq * 16 + 8] = u1;
  }
  __syncthreads();
  const int tid = threadIdx.x, lane = tid & 63, w = tid >> 6;
  const int fr = lane & 15, fq = lane >> 4, fk = fq * 8;
  const unsigned short* vt = vTb + (size_t)b * (Vv * Tt) + (size_t)c * CC;
  for (int vb4 = 0; vb4 < 4; ++vb4) {
    f32x4 acc[4][4] = {};
#pragma unroll
    for (int ks = 0; ks < 2; ++ks) {
      bf16x8 af[4], bf[4];
#pragma unroll
      for (int i = 0; i < 4; ++i)
        af[i] = *(const bf16x8*)&khs[w * 64 + i * 16 + fr][ks * 32 + fk];
#pragma unroll
      for (int j = 0; j < 4; ++j)
        bf[j] = *(const bf16x8*)(vt + (size_t)(vb4 * 64 + j * 16 + fr) * Tt + ks * 32 + fk);
#pragma unroll
      for (int i = 0; i < 4; ++i)
#pragma unroll
        for (int j = 0; j < 4; ++j)
          acc[i][j] = __builtin_amdgcn_mfma_f32_16x16x32_bf16(af[i], bf[j], acc[i][j], 0, 0, 0);
    }
#pragma unroll
    for (int i = 0; i < 4; ++i)
#pragma unroll
      for (int j = 0; j < 4; ++j)
#pragma unroll
        for (int r = 0; r < 4; ++r)
          Sb[(size_t)task * (Kk * Vv) + (size_t)(w * 64 + i * 16 + fq * 4 + r) * Vv +
             vb4 * 64 + j * 16 + fr] = f2b(acc[i][j][r]);
  }
}

// ---------------- passR: sequential chunk recombine (parallel over B,K,V) ----------------
__global__ __launch_bounds__(256) void passR_kernel(
    const unsigned short* __restrict__ Sb, const float* __restrict__ Dendb,
    unsigned short* __restrict__ S0Tb, float* __restrict__ state_out) {
  const int vt = blockIdx.x, kt = blockIdx.y, b = blockIdx.z;
  const int tid = threadIdx.x;
  const int kq = tid >> 2;
  const int vq = tid & 3;
  const int vr = tid >> 2;
  const int kqq = tid & 3;
  __shared__ __align__(16) unsigned short Ts[64][72];
  float st[16];
#pragma unroll
  for (int j = 0; j < 16; ++j) st[j] = 0.f;
  for (int c = 0; c < NC; ++c) {
    const int task = b * NC + c;
#pragma unroll
    for (int j = 0; j < 16; ++j) Ts[vq * 16 + j][kq] = f2b(st[j]);
    __syncthreads();
    {
      unsigned short* dst = S0Tb + (size_t)task * (Kk * Vv) +
                            (size_t)(vt * 64 + vr) * Kk + kt * 64 + kqq * 16;
      *(uint4*)dst = *(const uint4*)&Ts[vr][kqq * 16];
      *(uint4*)(dst + 8) = *(const uint4*)&Ts[vr][kqq * 16 + 8];
    }
    __syncthreads();
    const float d = Dendb[task * 256 + kt * 64 + kq];
    const unsigned short* sp = Sb + (size_t)task * (Kk * Vv) +
                               (size_t)(kt * 64 + kq) * Vv + vt * 64 + vq * 16;
#pragma unroll
    for (int h = 0; h < 2; ++h) {
      uint4 raw = *(const uint4*)(sp + h * 8);
      unsigned ws_[4] = {raw.x, raw.y, raw.z, raw.w};
#pragma unroll
      for (int e = 0; e < 4; ++e) {
        float lo = __uint_as_float(ws_[e] << 16);
        float hi = __uint_as_float(ws_[e] & 0xFFFF0000u);
        st[h * 8 + e * 2]     = d * st[h * 8 + e * 2] + lo;
        st[h * 8 + e * 2 + 1] = d * st[h * 8 + e * 2 + 1] + hi;
      }
    }
  }
  float* so = state_out + (size_t)(b * Kk + kt * 64 + kq) * Vv + vt * 64 + vq * 16;
#pragma unroll
  for (int j = 0; j < 16; ++j) so[j] = st[j];
}

// ---------------- passO: per (b,c): att = q2*S0 + tril(A)*v ----------------
__global__ __launch_bounds__(256) void passO_kernel(
    const unsigned short* __restrict__ qab, const unsigned short* __restrict__ kab,
    const unsigned short* __restrict__ q2b, const float* __restrict__ LBb,
    const unsigned short* __restrict__ S0Tb, const unsigned short* __restrict__ vTb,
    unsigned short* __restrict__ attb) {
  const int c = blockIdx.x, b = blockIdx.y;
  const int task = b * NC + c;
  const int tid = threadIdx.x, lane = tid & 63, w = tid >> 6;
  const int fr = lane & 15, fq = lane >> 4, fk = fq * 8;
  __shared__ float LB_s[4][256];
  __shared__ __align__(16) unsigned short A_s[64][72];
  const size_t tbase = (size_t)task * (CC * Kk);
  for (int idx = tid; idx < 1024; idx += 256) LB_s[idx >> 8][idx & 255] = LBb[(size_t)task * 1024 + idx];
  for (int idx = tid; idx < 64 * 72 / 2; idx += 256) ((unsigned*)A_s)[idx] = 0;
  __syncthreads();
  for (int p = w; p < 10; p += 4) {
    const int I = (p >= 6) ? 3 : (p >= 3) ? 2 : (p >= 1) ? 1 : 0;
    const int J = p - (I * (I + 1)) / 2;
    f32x4 acc = {0.f, 0.f, 0.f, 0.f};
#pragma unroll
    for (int ks = 0; ks < 8; ++ks) {
      const int k0 = ks * 32 + fk;
      bf16x8 af = *(const bf16x8*)(qab + tbase + (size_t)(I * 16 + fr) * Kk + k0);
      if (I != J) {
#pragma unroll
        for (int e = 0; e < 8; ++e) {
          float d = exp2f(LB_s[I][k0 + e] - LB_s[J][k0 + e]);
          af[e] = (__bf16)((float)af[e] * d);
        }
      }
      bf16x8 bf = *(const bf16x8*)(kab + tbase + (size_t)(J * 16 + fr) * Kk + k0);
      acc = __builtin_amdgcn_mfma_f32_16x16x32_bf16(af, bf, acc, 0, 0, 0);
    }
#pragma unroll
    for (int r = 0; r < 4; ++r) {
      const int ml = fq * 4 + r, nl = fr;
      bool keep = (I != J) || (nl <= ml);
      A_s[I * 16 + ml][J * 16 + nl] = keep ? f2b(acc[r]) : (unsigned short)0;
    }
  }
  __syncthreads();
  f32x4 acc2[4][4] = {};
  const unsigned short* q2t = q2b + tbase;
  const unsigned short* s0t = S0Tb + (size_t)task * (Kk * Vv);
  const unsigned short* vtp = vTb + (size_t)b * (Vv * Tt) + (size_t)c * CC;
  const int vbase = w * 64;
#pragma unroll
  for (int ks = 0; ks < 8; ++ks) {
    const int k0 = ks * 32 + fk;
    bf16x8 af[4], bf[4];
#pragma unroll
    for (int i = 0; i < 4; ++i) af[i] = *(const bf16x8*)(q2t + (size_t)(i * 16 + fr) * Kk + k0);
#pragma unroll
    for (int j = 0; j < 4; ++j) bf[j] = *(const bf16x8*)(s0t + (size_t)(vbase + j * 16 + fr) * Kk + k0);
#pragma unroll
    for (int i = 0; i < 4; ++i)
#pragma unroll
      for (int j = 0; j < 4; ++j)
        acc2[i][j] = __builtin_amdgcn_mfma_f32_16x16x32_bf16(af[i], bf[j], acc2[i][j], 0, 0, 0);
  }
#pragma unroll
  for (int ks = 0; ks < 2; ++ks) {
    const int s0 = ks * 32 + fk;
    bf16x8 af[4], bf[4];
#pragma unroll
    for (int i = 0; i < 4; ++i) af[i] = *(const bf16x8*)&A_s[i * 16 + fr][s0];
#pragma unroll
    for (int j = 0; j < 4; ++j) bf[j] = *(const bf16x8*)(vtp + (size_t)(vbase + j * 16 + fr) * Tt + s0);
#pragma unroll
    for (int i = 0; i < 4; ++i)
#pragma unroll
      for (int j = 0; j < 4; ++j)
        acc2[i][j] = __builtin_amdgcn_mfma_f32_16x16x32_bf16(af[i], bf[j], acc2[i][j], 0, 0, 0);
  }
#pragma unroll
  for (int i = 0; i < 4; ++i)
#pragma unroll
    for (int j = 0; j < 4; ++j)
#pragma unroll
      for (int r = 0; r < 4; ++r)
        attb[((size_t)b * Tt + c * CC + i * 16 + fq * 4 + r) * Vv + vbase + j * 16 + fr]
            = f2b(acc2[i][j][r]);
}

extern "C" void kernel_launch(void* const* d_in, const int* in_sizes, int n_in,
                              void* d_out, int out_size, void* d_ws, size_t ws_size,
                              hipStream_t stream) {
  const float* hs = (const float*)d_in[0];
  const float* Wq = (const float*)d_in[1];
  const float* bq = (const float*)d_in[2];
  const float* Wk = (const float*)d_in[3];
  const float* bk = (const float*)d_in[4];
  const float* Wv = (const float*)d_in[5];
  const float* bv = (const float*)d_in[6];
  const float* Wg = (const float*)d_in[7];
  const float* bg = (const float*)d_in[8];
  const float* Wo = (const float*)d_in[9];
  const float* bo = (const float*)d_in[10];

  float* out = (float*)d_out;
  float* state_out = out + (size_t)Bb * Tt * Oo;

  char* p = (char*)d_ws;
  auto alloc = [&](size_t bytes) {
    char* r = p;
    p += (bytes + 255) & ~(size_t)255;
    return r;
  };
  unsigned short* hsb   = (unsigned short*)alloc((size_t)Bb * Tt * Hh * 2);   // 32MB
  unsigned short* WallT = (unsigned short*)alloc((size_t)1024 * Hh * 2);      // 2MB
  unsigned short* WoT   = (unsigned short*)alloc((size_t)Oo * Vv * 2);
  unsigned short* qb    = (unsigned short*)alloc((size_t)Bb * Tt * Kk * 2);   // 8MB each
  unsigned short* kb    = (unsigned short*)alloc((size_t)Bb * Tt * Kk * 2);
  unsigned short* lgb   = (unsigned short*)alloc((size_t)Bb * Tt * Kk * 2);   // f16
  unsigned short* vb    = (unsigned short*)alloc((size_t)Bb * Tt * Vv * 2);
  unsigned short* vTb   = (unsigned short*)alloc((size_t)Bb * Vv * Tt * 2);
  unsigned short* attb  = (unsigned short*)alloc((size_t)Bb * Tt * Vv * 2);
  unsigned short* q2b   = (unsigned short*)alloc((size_t)Bb * Tt * Kk * 2);
  unsigned short* qab   = (unsigned short*)alloc((size_t)Bb * Tt * Kk * 2);
  unsigned short* kab   = (unsigned short*)alloc((size_t)Bb * Tt * Kk * 2);
  float*          LBb   = (float*)alloc((size_t)Bb * NC * 4 * Kk * 4);
  float*          Dendb = (float*)alloc((size_t)Bb * NC * Kk * 4);
  unsigned short* Sb    = (unsigned short*)alloc((size_t)Bb * NC * Kk * Vv * 2);  // 32MB
  unsigned short* S0Tb  = (unsigned short*)alloc((size_t)Bb * NC * Kk * Vv * 2);  // 32MB

  // 1) casts + weight transposes (concat projection weights into WallT rows)
  int n4 = Bb * Tt * Hh / 4;
  cast_bf16_kernel<<<(n4 + 255) / 256, 256, 0, stream>>>(hs, hsb, n4);
  transpose_cast_kernel<<<dim3(Hh / 32, Kk / 32), 256, 0, stream>>>(Wq, WallT + 0 * Kk * Hh, Hh, Kk);
  transpose_cast_kernel<<<dim3(Hh / 32, Kk / 32), 256, 0, stream>>>(Wk, WallT + 1 * Kk * Hh, Hh, Kk);
  transpose_cast_kernel<<<dim3(Hh / 32, Kk / 32), 256, 0, stream>>>(Wg, WallT + 2 * Kk * Hh, Hh, Kk);
  transpose_cast_kernel<<<dim3(Hh / 32, Kk / 32), 256, 0, stream>>>(Wv, WallT + 3 * Kk * Hh, Hh, Kk);
  transpose_cast_kernel<<<dim3(Vv / 32, Oo / 32), 256, 0, stream>>>(Wo, WoT, Vv, Oo);

  // 2) fused projections: one 128^2-tile GEMM, N=1024 (grid 1024 blocks = 4/CU)
  gemm_fused_kernel<0><<<dim3(1024 / BN, (Bb * Tt) / BM), 256, 0, stream>>>(
      hsb, WallT, bq, bk, bg, bv, nullptr, qb, kb, lgb, vb, Bb * Tt, 1024, Hh);

  // 3) vT: per-batch transpose (T x V -> V x T)
  transpose_b16_kernel<<<dim3(Tt / 32, Vv / 32, Bb), 256, 0, stream>>>(vb, vTb, Tt, Vv);

  // 4) fused prep + per-chunk state GEMM
  prep_sgemm_kernel<<<dim3(NC, Bb), 256, 0, stream>>>(qb, kb, lgb, vTb, q2b, qab, kab,
                                                      LBb, Dendb, Sb);

  // 5) sequential chunk recombine -> S0T (pre-chunk states) + final state
  passR_kernel<<<dim3(Vv / 64, Kk / 64, Bb), 256, 0, stream>>>(Sb, Dendb, S0Tb, state_out);

  // 6) outputs: att = q2.S0 + tril(A).v
  passO_kernel<<<dim3(NC, Bb), 256, 0, stream>>>(qab, kab, q2b, LBb, S0Tb, vTb, attb);

  // 7) output projection (f32 out to d_out)
  gemm_fused_kernel<1><<<dim3(Oo / BN, (Bb * Tt) / BM), 256, 0, stream>>>(
      attb, WoT, bo, nullptr, nullptr, nullptr, out, nullptr, nullptr, nullptr, nullptr,
      Bb * Tt, Oo, Vv);
}

// Round 8
// 268.636 us; speedup vs baseline: 1.2483x; 1.0530x over previous
//
#include <hip/hip_runtime.h>

// Problem dims (fixed by setup_inputs)
#define Bb 8
#define Tt 2048
#define Hh 1024
#define Kk 256
#define Vv 256
#define Oo 1024
#define CC 64   // chunk length
#define NC 32   // chunks per batch (Tt/CC)

typedef __attribute__((ext_vector_type(8))) __bf16 bf16x8;
typedef __attribute__((ext_vector_type(4))) float f32x4;

__device__ __forceinline__ unsigned short f2b(float f) {
  unsigned u = __float_as_uint(f);
  u = (u + 0x7FFFu + ((u >> 16) & 1u)) >> 16;
  return (unsigned short)u;
}
__device__ __forceinline__ float b2f(unsigned short u) {
  return __uint_as_float(((unsigned)u) << 16);
}
__device__ __forceinline__ void gload_lds16(const unsigned short* g, unsigned short* l) {
  __builtin_amdgcn_global_load_lds(
      (const __attribute__((address_space(1))) void*)g,
      (__attribute__((address_space(3))) void*)l, 16, 0, 0);
}

// ---------------- cast f32 -> bf16 (vectorized) ----------------
__global__ __launch_bounds__(256) void cast_bf16_kernel(const float* __restrict__ in,
                                                        unsigned short* __restrict__ out,
                                                        int n4) {
  int i = blockIdx.x * 256 + threadIdx.x;
  if (i >= n4) return;
  float4 v = ((const float4*)in)[i];
  ushort4 o;
  o.x = f2b(v.x); o.y = f2b(v.y); o.z = f2b(v.z); o.w = f2b(v.w);
  ((ushort4*)out)[i] = o;
}

// ---------------- transpose + cast: W (H x N) f32 -> WT (N x H) bf16 ----------------
__global__ __launch_bounds__(256) void transpose_cast_kernel(const float* __restrict__ W,
                                                             unsigned short* __restrict__ WT,
                                                             int H, int N) {
  __shared__ float tile[32][33];
  int h0 = blockIdx.x * 32, n0 = blockIdx.y * 32;
  int tx = threadIdx.x & 31, ty = threadIdx.x >> 5;
  for (int r = ty; r < 32; r += 8)
    tile[r][tx] = W[(size_t)(h0 + r) * N + n0 + tx];
  __syncthreads();
  for (int r = ty; r < 32; r += 8)
    WT[(size_t)(n0 + r) * H + h0 + tx] = f2b(tile[tx][r]);
}

// ---------------- batched bf16 transpose: in (R x C) -> out (C x R), z = matrix idx ----
__global__ __launch_bounds__(256) void transpose_b16_kernel(
    const unsigned short* __restrict__ in, unsigned short* __restrict__ out,
    int R, int C) {
  __shared__ unsigned short tile[32][33];
  const int r0 = blockIdx.x * 32, c0 = blockIdx.y * 32;
  const size_t base = (size_t)blockIdx.z * R * C;
  const int tx = threadIdx.x & 31, ty = threadIdx.x >> 5;
  for (int rr = ty; rr < 32; rr += 8)
    tile[rr][tx] = in[base + (size_t)(r0 + rr) * C + c0 + tx];
  __syncthreads();
  for (int rr = ty; rr < 32; rr += 8)
    out[base + (size_t)(c0 + rr) * R + r0 + tx] = tile[tx][rr];
}

// ---------------- proj GEMM: 128x128, BK=64, 4 waves, swizzled LDS, 4 blocks/CU ----
// C = A (MxK) * Bt^T; epilogue: block's n0>>8 selects {q, sigmoid->k, log2sig->g(f16), v}
#define BM 128
#define BN 128
#define BK 64

__global__ __launch_bounds__(256, 4) void gemm_proj_kernel(
    const unsigned short* __restrict__ A, const unsigned short* __restrict__ Bt,
    const float* __restrict__ b0p, const float* __restrict__ b1p,
    const float* __restrict__ b2p, const float* __restrict__ b3p,
    unsigned short* __restrict__ O0, unsigned short* __restrict__ O1,
    unsigned short* __restrict__ O2, unsigned short* __restrict__ O3,
    int M, int N, int K) {
  // LDS 32 KiB; __launch_bounds__(256,4) caps regs at 128 total (incl AGPR) -> 4 blocks/CU
  __shared__ __align__(16) unsigned short As[BM * BK];
  __shared__ __align__(16) unsigned short Bs[BN * BK];
  const int tid = threadIdx.x;
  const int lane = tid & 63, wid = tid >> 6;        // 4 waves
  const int wm = wid >> 1, wn = wid & 1;            // 2x2 wave grid; wave = 64x64 out
  const int lin = blockIdx.x + blockIdx.y * gridDim.x;
  const int cpx = (gridDim.x * gridDim.y) >> 3;
  const int swz = (lin & 7) * cpx + (lin >> 3);
  const int m0 = (swz / gridDim.x) * BM, n0 = (swz % gridDim.x) * BN;
  const int fr = lane & 15, fq = lane >> 4;
  // staging: per gload a wave writes 8 rows x 128B. Lane l -> row +(l>>3),
  // LDS 16B-chunk (l&7); global source chunk = (l&7) ^ (l>>3).
  const int srl = lane >> 3;
  const int scs = ((lane & 7) ^ srl) * 8;
  const unsigned short* gaBase = A + (size_t)(m0 + srl) * K + scs;
  const unsigned short* gbBase = Bt + (size_t)(n0 + srl) * K + scs;

  f32x4 acc[4][4] = {};
  const int nt = K / BK;
  for (int t = 0; t < nt; ++t) {
    const int k0 = t * BK;
    __syncthreads();  // previous iter's LDS reads done
#pragma unroll
    for (int inst = 0; inst < 4; ++inst) {
      const int rb = wid * 32 + inst * 8;
      gload_lds16(gaBase + (size_t)rb * K + k0, &As[rb * BK]);
      gload_lds16(gbBase + (size_t)rb * K + k0, &Bs[rb * BK]);
    }
    __syncthreads();  // staged data visible (drain hidden by co-resident blocks)
#pragma unroll
    for (int ks = 0; ks < 2; ++ks) {
      bf16x8 af[4], bfv[4];
#pragma unroll
      for (int j = 0; j < 4; ++j) {
        const int R = wn * 64 + j * 16 + fr;
        const int ch = ((ks << 2) | fq) ^ (fr & 7);
        bfv[j] = *(const bf16x8*)&Bs[R * BK + ch * 8];
      }
#pragma unroll
      for (int i = 0; i < 4; ++i) {
        const int R = wm * 64 + i * 16 + fr;
        const int ch = ((ks << 2) | fq) ^ (fr & 7);
        af[i] = *(const bf16x8*)&As[R * BK + ch * 8];
      }
#pragma unroll
      for (int i = 0; i < 4; ++i)
#pragma unroll
        for (int j = 0; j < 4; ++j)
          acc[i][j] = __builtin_amdgcn_mfma_f32_16x16x32_bf16(af[i], bfv[j], acc[i][j], 0, 0, 0);
    }
  }
  // epilogue: split q/k/g/v by 256-wide n-panel
  const int sel = n0 >> 8;
  const float* bp = sel == 0 ? b0p : sel == 1 ? b1p : sel == 2 ? b2p : b3p;
  unsigned short* Op = sel == 0 ? O0 : sel == 1 ? O1 : sel == 2 ? O2 : O3;
#pragma unroll
  for (int j = 0; j < 4; ++j) {
    const int nl = (n0 + wn * 64 + j * 16 + fr) & 255;
    const float bv = bp[nl];
#pragma unroll
    for (int i = 0; i < 4; ++i) {
      const int mb = m0 + wm * 64 + i * 16 + fq * 4;
#pragma unroll
      for (int r = 0; r < 4; ++r) {
        const int m = mb + r;
        const float x = acc[i][j][r] + bv;
        if (sel == 0) {
          Op[(size_t)m * Kk + nl] = f2b(x);
        } else if (sel == 1) {
          Op[(size_t)m * Kk + nl] = f2b(1.f / (1.f + expf(-x)));
        } else if (sel == 2) {
          float e = exp2f(-x * 1.44269504f);
          float lg = -log2f(1.f + e);
          _Float16 hv = (_Float16)lg;
          unsigned short u;
          __builtin_memcpy(&u, &hv, 2);
          Op[(size_t)m * Kk + nl] = u;
        } else {  // v plain (coalesced); transposed later
          Op[(size_t)m * Vv + nl] = f2b(x);
        }
      }
    }
  }
}

// ---------------- out-proj GEMM: K=256 one-shot staged (128 KiB LDS, 1 barrier) ------
// C (f32) = A (Mx256 bf16) * Bt^T (Nx256 bf16) + bias
__global__ __launch_bounds__(256) void gemm_oneshot_kernel(
    const unsigned short* __restrict__ A, const unsigned short* __restrict__ Bt,
    const float* __restrict__ bias, float* __restrict__ Cf, int M, int N) {
  // Full A-tile 128x256 (64 KiB) + B-tile 128x256 (64 KiB) staged once; single drain.
  // Rows are 512B = 32 chunks of 16B; LDS slot c' of row R holds global chunk c'^(R&7)
  // (source pre-swizzled, LDS write linear); reads XOR the same -> 2-way (free).
  __shared__ __align__(16) unsigned short As[128 * 256];
  __shared__ __align__(16) unsigned short Bs[128 * 256];
  const int tid = threadIdx.x, lane = tid & 63, wid = tid >> 6;
  const int wm = wid >> 1, wn = wid & 1;
  const int lin = blockIdx.x + blockIdx.y * gridDim.x;
  const int cpx = (gridDim.x * gridDim.y) >> 3;
  const int swz = (lin & 7) * cpx + (lin >> 3);
  const int m0 = (swz / gridDim.x) * 128, n0 = (swz % gridDim.x) * 128;
  const int fr = lane & 15, fq = lane >> 4;
  const int lrow = lane >> 5;   // 0/1: which of the 2 rows this gload covers
  const int lch = lane & 31;    // LDS chunk within row
#pragma unroll
  for (int i = 0; i < 16; ++i) {
    const int R0 = wid * 32 + i * 2;           // wave-uniform row base
    const int R = R0 + lrow;
    const int sc = (lch ^ (R & 7)) * 8;        // pre-swizzled source chunk
    gload_lds16(A + (size_t)(m0 + R) * 256 + sc, &As[R0 * 256]);
    gload_lds16(Bt + (size_t)(n0 + R) * 256 + sc, &Bs[R0 * 256]);
  }
  __syncthreads();  // single vmcnt drain for the whole K range
  f32x4 acc[4][4] = {};
#pragma unroll
  for (int ks = 0; ks < 8; ++ks) {
    bf16x8 af[4], bfv[4];
#pragma unroll
    for (int i = 0; i < 4; ++i) {
      const int R = wm * 64 + i * 16 + fr;
      const int ch = (ks * 4 + fq) ^ (R & 7);
      af[i] = *(const bf16x8*)&As[R * 256 + ch * 8];
    }
#pragma unroll
    for (int j = 0; j < 4; ++j) {
      const int R = wn * 64 + j * 16 + fr;
      const int ch = (ks * 4 + fq) ^ (R & 7);
      bfv[j] = *(const bf16x8*)&Bs[R * 256 + ch * 8];
    }
#pragma unroll
    for (int i = 0; i < 4; ++i)
#pragma unroll
      for (int j = 0; j < 4; ++j)
        acc[i][j] = __builtin_amdgcn_mfma_f32_16x16x32_bf16(af[i], bfv[j], acc[i][j], 0, 0, 0);
  }
#pragma unroll
  for (int j = 0; j < 4; ++j) {
    const int n = n0 + wn * 64 + j * 16 + fr;
    const float bv = bias[n];
#pragma unroll
    for (int i = 0; i < 4; ++i) {
      const int mb = m0 + wm * 64 + i * 16 + fq * 4;
#pragma unroll
      for (int r = 0; r < 4; ++r)
        Cf[(size_t)(mb + r) * N + n] = acc[i][j][r] + bv;
    }
  }
}

// ---------------- fused prep+sgemm: per (b,c) task ----------------
__global__ __launch_bounds__(256) void prep_sgemm_kernel(
    const unsigned short* __restrict__ qb, const unsigned short* __restrict__ kb,
    const unsigned short* __restrict__ lgb, const unsigned short* __restrict__ vTb,
    unsigned short* __restrict__ q2b, unsigned short* __restrict__ qab,
    unsigned short* __restrict__ kab,
    float* __restrict__ LBb, float* __restrict__ Dendb,
    unsigned short* __restrict__ Sb) {
  __shared__ __align__(16) unsigned short khs[256][72];
  const int c = blockIdx.x, b = blockIdx.y;
  const int k = threadIdx.x;
  const int task = b * NC + c;
  const size_t rowbase = ((size_t)b * Tt + (size_t)c * CC) * Kk + k;
  float Ls = 0.f;
  float LBr[4];
#pragma unroll
  for (int gq = 0; gq < 4; ++gq) {
    LBr[gq] = Ls;
#pragma unroll
    for (int tt = 0; tt < 16; ++tt) {
      int t = gq * 16 + tt;
      _Float16 hv;
      __builtin_memcpy(&hv, &lgb[rowbase + (size_t)t * Kk], 2);
      Ls += (float)hv;
    }
  }
  const float Lend = Ls;
#pragma unroll
  for (int gq = 0; gq < 4; ++gq) LBb[(size_t)task * 1024 + gq * 256 + k] = LBr[gq];
  Dendb[task * 256 + k] = exp2f(Lend);
  float L = 0.f;
#pragma unroll
  for (int gq = 0; gq < 4; ++gq) {
    const float LBc = LBr[gq];
    unsigned kw[8];
#pragma unroll
    for (int tt = 0; tt < 16; ++tt) {
      int t = gq * 16 + tt;
      size_t off = rowbase + (size_t)t * Kk;
      _Float16 hv;
      __builtin_memcpy(&hv, &lgb[off], 2);
      L += (float)hv;
      float qv = b2f(qb[off]);
      float kv = b2f(kb[off]);
      q2b[off] = f2b(qv * exp2f(L));
      qab[off] = f2b(qv * exp2f(L - LBc));
      kab[off] = f2b(kv * exp2f(LBc - L));
      unsigned short kh = f2b(kv * exp2f(Lend - L));
      if (tt & 1) kw[tt >> 1] |= ((unsigned)kh) << 16;
      else        kw[tt >> 1] = kh;
    }
    uint4 u0; u0.x = kw[0]; u0.y = kw[1]; u0.z = kw[2]; u0.w = kw[3];
    uint4 u1; u1.x = kw[4]; u1.y = kw[5]; u1.z = kw[6]; u1.w = kw[7];
    *(uint4*)&khs[k][gq * 16] = u0;
    *(uint4*)&khs[k][gq * 16 + 8] = u1;
  }
  __syncthreads();
  const int tid = threadIdx.x, lane = tid & 63, w = tid >> 6;
  const int fr = lane & 15, fq = lane >> 4, fk = fq * 8;
  const unsigned short* vt = vTb + (size_t)b * (Vv * Tt) + (size_t)c * CC;
  for (int vb4 = 0; vb4 < 4; ++vb4) {
    f32x4 acc[4][4] = {};
#pragma unroll
    for (int ks = 0; ks < 2; ++ks) {
      bf16x8 af[4], bf[4];
#pragma unroll
      for (int i = 0; i < 4; ++i)
        af[i] = *(const bf16x8*)&khs[w * 64 + i * 16 + fr][ks * 32 + fk];
#pragma unroll
      for (int j = 0; j < 4; ++j)
        bf[j] = *(const bf16x8*)(vt + (size_t)(vb4 * 64 + j * 16 + fr) * Tt + ks * 32 + fk);
#pragma unroll
      for (int i = 0; i < 4; ++i)
#pragma unroll
        for (int j = 0; j < 4; ++j)
          acc[i][j] = __builtin_amdgcn_mfma_f32_16x16x32_bf16(af[i], bf[j], acc[i][j], 0, 0, 0);
    }
#pragma unroll
    for (int i = 0; i < 4; ++i)
#pragma unroll
      for (int j = 0; j < 4; ++j)
#pragma unroll
        for (int r = 0; r < 4; ++r)
          Sb[(size_t)task * (Kk * Vv) + (size_t)(w * 64 + i * 16 + fq * 4 + r) * Vv +
             vb4 * 64 + j * 16 + fr] = f2b(acc[i][j][r]);
  }
}

// ---------------- passR: sequential chunk recombine (parallel over B,K,V) ----------------
__global__ __launch_bounds__(256) void passR_kernel(
    const unsigned short* __restrict__ Sb, const float* __restrict__ Dendb,
    unsigned short* __restrict__ S0Tb, float* __restrict__ state_out) {
  const int vt = blockIdx.x, kt = blockIdx.y, b = blockIdx.z;
  const int tid = threadIdx.x;
  const int kq = tid >> 2;
  const int vq = tid & 3;
  const int vr = tid >> 2;
  const int kqq = tid & 3;
  __shared__ __align__(16) unsigned short Ts[64][72];
  float st[16];
#pragma unroll
  for (int j = 0; j < 16; ++j) st[j] = 0.f;
  for (int c = 0; c < NC; ++c) {
    const int task = b * NC + c;
#pragma unroll
    for (int j = 0; j < 16; ++j) Ts[vq * 16 + j][kq] = f2b(st[j]);
    __syncthreads();
    {
      unsigned short* dst = S0Tb + (size_t)task * (Kk * Vv) +
                            (size_t)(vt * 64 + vr) * Kk + kt * 64 + kqq * 16;
      *(uint4*)dst = *(const uint4*)&Ts[vr][kqq * 16];
      *(uint4*)(dst + 8) = *(const uint4*)&Ts[vr][kqq * 16 + 8];
    }
    __syncthreads();
    const float d = Dendb[task * 256 + kt * 64 + kq];
    const unsigned short* sp = Sb + (size_t)task * (Kk * Vv) +
                               (size_t)(kt * 64 + kq) * Vv + vt * 64 + vq * 16;
#pragma unroll
    for (int h = 0; h < 2; ++h) {
      uint4 raw = *(const uint4*)(sp + h * 8);
      unsigned ws_[4] = {raw.x, raw.y, raw.z, raw.w};
#pragma unroll
      for (int e = 0; e < 4; ++e) {
        float lo = __uint_as_float(ws_[e] << 16);
        float hi = __uint_as_float(ws_[e] & 0xFFFF0000u);
        st[h * 8 + e * 2]     = d * st[h * 8 + e * 2] + lo;
        st[h * 8 + e * 2 + 1] = d * st[h * 8 + e * 2 + 1] + hi;
      }
    }
  }
  float* so = state_out + (size_t)(b * Kk + kt * 64 + kq) * Vv + vt * 64 + vq * 16;
#pragma unroll
  for (int j = 0; j < 16; ++j) so[j] = st[j];
}

// ---------------- passO: per (b,c): att = q2*S0 + tril(A)*v ----------------
__global__ __launch_bounds__(256) void passO_kernel(
    const unsigned short* __restrict__ qab, const unsigned short* __restrict__ kab,
    const unsigned short* __restrict__ q2b, const float* __restrict__ LBb,
    const unsigned short* __restrict__ S0Tb, const unsigned short* __restrict__ vTb,
    unsigned short* __restrict__ attb) {
  const int c = blockIdx.x, b = blockIdx.y;
  const int task = b * NC + c;
  const int tid = threadIdx.x, lane = tid & 63, w = tid >> 6;
  const int fr = lane & 15, fq = lane >> 4, fk = fq * 8;
  __shared__ float LB_s[4][256];
  __shared__ __align__(16) unsigned short A_s[64][72];
  const size_t tbase = (size_t)task * (CC * Kk);
  for (int idx = tid; idx < 1024; idx += 256) LB_s[idx >> 8][idx & 255] = LBb[(size_t)task * 1024 + idx];
  for (int idx = tid; idx < 64 * 72 / 2; idx += 256) ((unsigned*)A_s)[idx] = 0;
  __syncthreads();
  for (int p = w; p < 10; p += 4) {
    const int I = (p >= 6) ? 3 : (p >= 3) ? 2 : (p >= 1) ? 1 : 0;
    const int J = p - (I * (I + 1)) / 2;
    f32x4 acc = {0.f, 0.f, 0.f, 0.f};
#pragma unroll
    for (int ks = 0; ks < 8; ++ks) {
      const int k0 = ks * 32 + fk;
      bf16x8 af = *(const bf16x8*)(qab + tbase + (size_t)(I * 16 + fr) * Kk + k0);
      if (I != J) {
#pragma unroll
        for (int e = 0; e < 8; ++e) {
          float d = exp2f(LB_s[I][k0 + e] - LB_s[J][k0 + e]);
          af[e] = (__bf16)((float)af[e] * d);
        }
      }
      bf16x8 bf = *(const bf16x8*)(kab + tbase + (size_t)(J * 16 + fr) * Kk + k0);
      acc = __builtin_amdgcn_mfma_f32_16x16x32_bf16(af, bf, acc, 0, 0, 0);
    }
#pragma unroll
    for (int r = 0; r < 4; ++r) {
      const int ml = fq * 4 + r, nl = fr;
      bool keep = (I != J) || (nl <= ml);
      A_s[I * 16 + ml][J * 16 + nl] = keep ? f2b(acc[r]) : (unsigned short)0;
    }
  }
  __syncthreads();
  f32x4 acc2[4][4] = {};
  const unsigned short* q2t = q2b + tbase;
  const unsigned short* s0t = S0Tb + (size_t)task * (Kk * Vv);
  const unsigned short* vtp = vTb + (size_t)b * (Vv * Tt) + (size_t)c * CC;
  const int vbase = w * 64;
#pragma unroll
  for (int ks = 0; ks < 8; ++ks) {
    const int k0 = ks * 32 + fk;
    bf16x8 af[4], bf[4];
#pragma unroll
    for (int i = 0; i < 4; ++i) af[i] = *(const bf16x8*)(q2t + (size_t)(i * 16 + fr) * Kk + k0);
#pragma unroll
    for (int j = 0; j < 4; ++j) bf[j] = *(const bf16x8*)(s0t + (size_t)(vbase + j * 16 + fr) * Kk + k0);
#pragma unroll
    for (int i = 0; i < 4; ++i)
#pragma unroll
      for (int j = 0; j < 4; ++j)
        acc2[i][j] = __builtin_amdgcn_mfma_f32_16x16x32_bf16(af[i], bf[j], acc2[i][j], 0, 0, 0);
  }
#pragma unroll
  for (int ks = 0; ks < 2; ++ks) {
    const int s0 = ks * 32 + fk;
    bf16x8 af[4], bf[4];
#pragma unroll
    for (int i = 0; i < 4; ++i) af[i] = *(const bf16x8*)&A_s[i * 16 + fr][s0];
#pragma unroll
    for (int j = 0; j < 4; ++j) bf[j] = *(const bf16x8*)(vtp + (size_t)(vbase + j * 16 + fr) * Tt + s0);
#pragma unroll
    for (int i = 0; i < 4; ++i)
#pragma unroll
      for (int j = 0; j < 4; ++j)
        acc2[i][j] = __builtin_amdgcn_mfma_f32_16x16x32_bf16(af[i], bf[j], acc2[i][j], 0, 0, 0);
  }
#pragma unroll
  for (int i = 0; i < 4; ++i)
#pragma unroll
    for (int j = 0; j < 4; ++j)
#pragma unroll
      for (int r = 0; r < 4; ++r)
        attb[((size_t)b * Tt + c * CC + i * 16 + fq * 4 + r) * Vv + vbase + j * 16 + fr]
            = f2b(acc2[i][j][r]);
}

extern "C" void kernel_launch(void* const* d_in, const int* in_sizes, int n_in,
                              void* d_out, int out_size, void* d_ws, size_t ws_size,
                              hipStream_t stream) {
  const float* hs = (const float*)d_in[0];
  const float* Wq = (const float*)d_in[1];
  const float* bq = (const float*)d_in[2];
  const float* Wk = (const float*)d_in[3];
  const float* bk = (const float*)d_in[4];
  const float* Wv = (const float*)d_in[5];
  const float* bv = (const float*)d_in[6];
  const float* Wg = (const float*)d_in[7];
  const float* bg = (const float*)d_in[8];
  const float* Wo = (const float*)d_in[9];
  const float* bo = (const float*)d_in[10];

  float* out = (float*)d_out;
  float* state_out = out + (size_t)Bb * Tt * Oo;

  char* p = (char*)d_ws;
  auto alloc = [&](size_t bytes) {
    char* r = p;
    p += (bytes + 255) & ~(size_t)255;
    return r;
  };
  unsigned short* hsb   = (unsigned short*)alloc((size_t)Bb * Tt * Hh * 2);   // 32MB
  unsigned short* WallT = (unsigned short*)alloc((size_t)1024 * Hh * 2);      // 2MB
  unsigned short* WoT   = (unsigned short*)alloc((size_t)Oo * Vv * 2);
  unsigned short* qb    = (unsigned short*)alloc((size_t)Bb * Tt * Kk * 2);   // 8MB each
  unsigned short* kb    = (unsigned short*)alloc((size_t)Bb * Tt * Kk * 2);
  unsigned short* lgb   = (unsigned short*)alloc((size_t)Bb * Tt * Kk * 2);   // f16
  unsigned short* vb    = (unsigned short*)alloc((size_t)Bb * Tt * Vv * 2);
  unsigned short* vTb   = (unsigned short*)alloc((size_t)Bb * Vv * Tt * 2);
  unsigned short* attb  = (unsigned short*)alloc((size_t)Bb * Tt * Vv * 2);
  unsigned short* q2b   = (unsigned short*)alloc((size_t)Bb * Tt * Kk * 2);
  unsigned short* qab   = (unsigned short*)alloc((size_t)Bb * Tt * Kk * 2);
  unsigned short* kab   = (unsigned short*)alloc((size_t)Bb * Tt * Kk * 2);
  float*          LBb   = (float*)alloc((size_t)Bb * NC * 4 * Kk * 4);
  float*          Dendb = (float*)alloc((size_t)Bb * NC * Kk * 4);
  unsigned short* Sb    = (unsigned short*)alloc((size_t)Bb * NC * Kk * Vv * 2);  // 32MB
  unsigned short* S0Tb  = (unsigned short*)alloc((size_t)Bb * NC * Kk * Vv * 2);  // 32MB

  // 1) casts + weight transposes (concat projection weights into WallT rows)
  int n4 = Bb * Tt * Hh / 4;
  cast_bf16_kernel<<<(n4 + 255) / 256, 256, 0, stream>>>(hs, hsb, n4);
  transpose_cast_kernel<<<dim3(Hh / 32, Kk / 32), 256, 0, stream>>>(Wq, WallT + 0 * Kk * Hh, Hh, Kk);
  transpose_cast_kernel<<<dim3(Hh / 32, Kk / 32), 256, 0, stream>>>(Wk, WallT + 1 * Kk * Hh, Hh, Kk);
  transpose_cast_kernel<<<dim3(Hh / 32, Kk / 32), 256, 0, stream>>>(Wg, WallT + 2 * Kk * Hh, Hh, Kk);
  transpose_cast_kernel<<<dim3(Hh / 32, Kk / 32), 256, 0, stream>>>(Wv, WallT + 3 * Kk * Hh, Hh, Kk);
  transpose_cast_kernel<<<dim3(Vv / 32, Oo / 32), 256, 0, stream>>>(Wo, WoT, Vv, Oo);

  // 2) fused projections: one 128^2-tile GEMM, N=1024 (grid 1024 blocks, 4/CU)
  gemm_proj_kernel<<<dim3(1024 / BN, (Bb * Tt) / BM), 256, 0, stream>>>(
      hsb, WallT, bq, bk, bg, bv, qb, kb, lgb, vb, Bb * Tt, 1024, Hh);

  // 3) vT: per-batch transpose (T x V -> V x T)
  transpose_b16_kernel<<<dim3(Tt / 32, Vv / 32, Bb), 256, 0, stream>>>(vb, vTb, Tt, Vv);

  // 4) fused prep + per-chunk state GEMM
  prep_sgemm_kernel<<<dim3(NC, Bb), 256, 0, stream>>>(qb, kb, lgb, vTb, q2b, qab, kab,
                                                      LBb, Dendb, Sb);

  // 5) sequential chunk recombine -> S0T (pre-chunk states) + final state
  passR_kernel<<<dim3(Vv / 64, Kk / 64, Bb), 256, 0, stream>>>(Sb, Dendb, S0Tb, state_out);

  // 6) outputs: att = q2.S0 + tril(A).v
  passO_kernel<<<dim3(NC, Bb), 256, 0, stream>>>(qab, kab, q2b, LBb, S0Tb, vTb, attb);

  // 7) output projection: K=256 one-shot kernel (f32 out to d_out)
  gemm_oneshot_kernel<<<dim3(Oo / 128, (Bb * Tt) / 128), 256, 0, stream>>>(
      attb, WoT, bo, out, Bb * Tt, Oo);
}

// Round 9
// 239.896 us; speedup vs baseline: 1.3978x; 1.1198x over previous
//
#include <hip/hip_runtime.h>

// Problem dims (fixed by setup_inputs)
#define Bb 8
#define Tt 2048
#define Hh 1024
#define Kk 256
#define Vv 256
#define Oo 1024
#define CC 64   // chunk length
#define NC 32   // chunks per batch (Tt/CC)

typedef __attribute__((ext_vector_type(8))) __bf16 bf16x8;
typedef __attribute__((ext_vector_type(4))) float f32x4;

__device__ __forceinline__ unsigned short f2b(float f) {
  unsigned u = __float_as_uint(f);
  u = (u + 0x7FFFu + ((u >> 16) & 1u)) >> 16;
  return (unsigned short)u;
}
__device__ __forceinline__ float b2f(unsigned short u) {
  return __uint_as_float(((unsigned)u) << 16);
}
__device__ __forceinline__ void gload_lds16(const unsigned short* g, unsigned short* l) {
  __builtin_amdgcn_global_load_lds(
      (const __attribute__((address_space(1))) void*)g,
      (__attribute__((address_space(3))) void*)l, 16, 0, 0);
}

// ---------------- cast f32 -> bf16 (vectorized) ----------------
__global__ __launch_bounds__(256) void cast_bf16_kernel(const float* __restrict__ in,
                                                        unsigned short* __restrict__ out,
                                                        int n4) {
  int i = blockIdx.x * 256 + threadIdx.x;
  if (i >= n4) return;
  float4 v = ((const float4*)in)[i];
  ushort4 o;
  o.x = f2b(v.x); o.y = f2b(v.y); o.z = f2b(v.z); o.w = f2b(v.w);
  ((ushort4*)out)[i] = o;
}

// ---------------- transpose + cast: W (H x N) f32 -> WT (N x H) bf16 ----------------
__global__ __launch_bounds__(256) void transpose_cast_kernel(const float* __restrict__ W,
                                                             unsigned short* __restrict__ WT,
                                                             int H, int N) {
  __shared__ float tile[32][33];
  int h0 = blockIdx.x * 32, n0 = blockIdx.y * 32;
  int tx = threadIdx.x & 31, ty = threadIdx.x >> 5;
  for (int r = ty; r < 32; r += 8)
    tile[r][tx] = W[(size_t)(h0 + r) * N + n0 + tx];
  __syncthreads();
  for (int r = ty; r < 32; r += 8)
    WT[(size_t)(n0 + r) * H + h0 + tx] = f2b(tile[tx][r]);
}

// ---------------- batched bf16 transpose: in (R x C) -> out (C x R), z = matrix idx ----
__global__ __launch_bounds__(256) void transpose_b16_kernel(
    const unsigned short* __restrict__ in, unsigned short* __restrict__ out,
    int R, int C) {
  __shared__ unsigned short tile[32][33];
  const int r0 = blockIdx.x * 32, c0 = blockIdx.y * 32;
  const size_t base = (size_t)blockIdx.z * R * C;
  const int tx = threadIdx.x & 31, ty = threadIdx.x >> 5;
  for (int rr = ty; rr < 32; rr += 8)
    tile[rr][tx] = in[base + (size_t)(r0 + rr) * C + c0 + tx];
  __syncthreads();
  for (int rr = ty; rr < 32; rr += 8)
    out[base + (size_t)(c0 + rr) * R + r0 + tx] = tile[tx][rr];
}

// ---------------- GEMM: 128x128, BK=64, 4 waves, swizzled LDS, 4 blocks/CU ----
// C = A (MxK) * Bt^T
// MODE 0: proj epilogue: block's n0>>8 selects {q, sigmoid->k, log2sig->g(f16), v}
// MODE 1: f32 out + bias b0p
#define BM 128
#define BN 128
#define BK 64

template <int MODE>
__global__ __launch_bounds__(256, 4) void gemm_mf_kernel(
    const unsigned short* __restrict__ A, const unsigned short* __restrict__ Bt,
    const float* __restrict__ b0p, const float* __restrict__ b1p,
    const float* __restrict__ b2p, const float* __restrict__ b3p,
    float* __restrict__ Cf,
    unsigned short* __restrict__ O0, unsigned short* __restrict__ O1,
    unsigned short* __restrict__ O2, unsigned short* __restrict__ O3,
    int M, int N, int K) {
  // LDS 32 KiB; (256,4) caps regs at 128 total (incl AGPR) -> 4 blocks/CU
  __shared__ __align__(16) unsigned short As[BM * BK];
  __shared__ __align__(16) unsigned short Bs[BN * BK];
  const int tid = threadIdx.x;
  const int lane = tid & 63, wid = tid >> 6;        // 4 waves
  const int wm = wid >> 1, wn = wid & 1;            // 2x2 wave grid; wave = 64x64 out
  const int lin = blockIdx.x + blockIdx.y * gridDim.x;
  const int cpx = (gridDim.x * gridDim.y) >> 3;
  const int swz = (lin & 7) * cpx + (lin >> 3);
  const int m0 = (swz / gridDim.x) * BM, n0 = (swz % gridDim.x) * BN;
  const int fr = lane & 15, fq = lane >> 4;
  // staging: per gload a wave writes 8 rows x 128B. Lane l -> row +(l>>3),
  // LDS 16B-chunk (l&7); global source chunk = (l&7) ^ (l>>3).
  const int srl = lane >> 3;
  const int scs = ((lane & 7) ^ srl) * 8;
  const unsigned short* gaBase = A + (size_t)(m0 + srl) * K + scs;
  const unsigned short* gbBase = Bt + (size_t)(n0 + srl) * K + scs;

  f32x4 acc[4][4] = {};
  const int nt = K / BK;
  for (int t = 0; t < nt; ++t) {
    const int k0 = t * BK;
    __syncthreads();  // previous iter's LDS reads done
#pragma unroll
    for (int inst = 0; inst < 4; ++inst) {
      const int rb = wid * 32 + inst * 8;
      gload_lds16(gaBase + (size_t)rb * K + k0, &As[rb * BK]);
      gload_lds16(gbBase + (size_t)rb * K + k0, &Bs[rb * BK]);
    }
    __syncthreads();  // staged data visible (drain hidden by co-resident blocks)
#pragma unroll
    for (int ks = 0; ks < 2; ++ks) {
      bf16x8 af[4], bfv[4];
#pragma unroll
      for (int j = 0; j < 4; ++j) {
        const int R = wn * 64 + j * 16 + fr;
        const int ch = ((ks << 2) | fq) ^ (fr & 7);
        bfv[j] = *(const bf16x8*)&Bs[R * BK + ch * 8];
      }
#pragma unroll
      for (int i = 0; i < 4; ++i) {
        const int R = wm * 64 + i * 16 + fr;
        const int ch = ((ks << 2) | fq) ^ (fr & 7);
        af[i] = *(const bf16x8*)&As[R * BK + ch * 8];
      }
#pragma unroll
      for (int i = 0; i < 4; ++i)
#pragma unroll
        for (int j = 0; j < 4; ++j)
          acc[i][j] = __builtin_amdgcn_mfma_f32_16x16x32_bf16(af[i], bfv[j], acc[i][j], 0, 0, 0);
    }
  }
  // epilogue
  if (MODE == 1) {
#pragma unroll
    for (int j = 0; j < 4; ++j) {
      const int n = n0 + wn * 64 + j * 16 + fr;
      const float bv = b0p[n];
#pragma unroll
      for (int i = 0; i < 4; ++i) {
        const int mb = m0 + wm * 64 + i * 16 + fq * 4;
#pragma unroll
        for (int r = 0; r < 4; ++r)
          Cf[(size_t)(mb + r) * N + n] = acc[i][j][r] + bv;
      }
    }
  } else {
    const int sel = n0 >> 8;
    const float* bp = sel == 0 ? b0p : sel == 1 ? b1p : sel == 2 ? b2p : b3p;
    unsigned short* Op = sel == 0 ? O0 : sel == 1 ? O1 : sel == 2 ? O2 : O3;
#pragma unroll
    for (int j = 0; j < 4; ++j) {
      const int nl = (n0 + wn * 64 + j * 16 + fr) & 255;
      const float bv = bp[nl];
#pragma unroll
      for (int i = 0; i < 4; ++i) {
        const int mb = m0 + wm * 64 + i * 16 + fq * 4;
#pragma unroll
        for (int r = 0; r < 4; ++r) {
          const int m = mb + r;
          const float x = acc[i][j][r] + bv;
          if (sel == 0) {
            Op[(size_t)m * Kk + nl] = f2b(x);
          } else if (sel == 1) {
            Op[(size_t)m * Kk + nl] = f2b(1.f / (1.f + expf(-x)));
          } else if (sel == 2) {
            float e = exp2f(-x * 1.44269504f);
            float lg = -log2f(1.f + e);
            _Float16 hv = (_Float16)lg;
            unsigned short u;
            __builtin_memcpy(&u, &hv, 2);
            Op[(size_t)m * Kk + nl] = u;
          } else {  // v plain (coalesced); transposed later
            Op[(size_t)m * Vv + nl] = f2b(x);
          }
        }
      }
    }
  }
}

// ---------------- fused prep+sgemm: per (b,c) task ----------------
__global__ __launch_bounds__(256) void prep_sgemm_kernel(
    const unsigned short* __restrict__ qb, const unsigned short* __restrict__ kb,
    const unsigned short* __restrict__ lgb, const unsigned short* __restrict__ vTb,
    unsigned short* __restrict__ q2b, unsigned short* __restrict__ qab,
    unsigned short* __restrict__ kab,
    float* __restrict__ LBb, float* __restrict__ Dendb,
    unsigned short* __restrict__ Sb) {
  __shared__ __align__(16) unsigned short khs[256][72];
  const int c = blockIdx.x, b = blockIdx.y;
  const int k = threadIdx.x;
  const int task = b * NC + c;
  const size_t rowbase = ((size_t)b * Tt + (size_t)c * CC) * Kk + k;
  float Ls = 0.f;
  float LBr[4];
#pragma unroll
  for (int gq = 0; gq < 4; ++gq) {
    LBr[gq] = Ls;
#pragma unroll
    for (int tt = 0; tt < 16; ++tt) {
      int t = gq * 16 + tt;
      _Float16 hv;
      __builtin_memcpy(&hv, &lgb[rowbase + (size_t)t * Kk], 2);
      Ls += (float)hv;
    }
  }
  const float Lend = Ls;
#pragma unroll
  for (int gq = 0; gq < 4; ++gq) LBb[(size_t)task * 1024 + gq * 256 + k] = LBr[gq];
  Dendb[task * 256 + k] = exp2f(Lend);
  float L = 0.f;
#pragma unroll
  for (int gq = 0; gq < 4; ++gq) {
    const float LBc = LBr[gq];
    unsigned kw[8];
#pragma unroll
    for (int tt = 0; tt < 16; ++tt) {
      int t = gq * 16 + tt;
      size_t off = rowbase + (size_t)t * Kk;
      _Float16 hv;
      __builtin_memcpy(&hv, &lgb[off], 2);
      L += (float)hv;
      float qv = b2f(qb[off]);
      float kv = b2f(kb[off]);
      q2b[off] = f2b(qv * exp2f(L));
      qab[off] = f2b(qv * exp2f(L - LBc));
      kab[off] = f2b(kv * exp2f(LBc - L));
      unsigned short kh = f2b(kv * exp2f(Lend - L));
      if (tt & 1) kw[tt >> 1] |= ((unsigned)kh) << 16;
      else        kw[tt >> 1] = kh;
    }
    uint4 u0; u0.x = kw[0]; u0.y = kw[1]; u0.z = kw[2]; u0.w = kw[3];
    uint4 u1; u1.x = kw[4]; u1.y = kw[5]; u1.z = kw[6]; u1.w = kw[7];
    *(uint4*)&khs[k][gq * 16] = u0;
    *(uint4*)&khs[k][gq * 16 + 8] = u1;
  }
  __syncthreads();
  const int tid = threadIdx.x, lane = tid & 63, w = tid >> 6;
  const int fr = lane & 15, fq = lane >> 4, fk = fq * 8;
  const unsigned short* vt = vTb + (size_t)b * (Vv * Tt) + (size_t)c * CC;
  for (int vb4 = 0; vb4 < 4; ++vb4) {
    f32x4 acc[4][4] = {};
#pragma unroll
    for (int ks = 0; ks < 2; ++ks) {
      bf16x8 af[4], bf[4];
#pragma unroll
      for (int i = 0; i < 4; ++i)
        af[i] = *(const bf16x8*)&khs[w * 64 + i * 16 + fr][ks * 32 + fk];
#pragma unroll
      for (int j = 0; j < 4; ++j)
        bf[j] = *(const bf16x8*)(vt + (size_t)(vb4 * 64 + j * 16 + fr) * Tt + ks * 32 + fk);
#pragma unroll
      for (int i = 0; i < 4; ++i)
#pragma unroll
        for (int j = 0; j < 4; ++j)
          acc[i][j] = __builtin_amdgcn_mfma_f32_16x16x32_bf16(af[i], bf[j], acc[i][j], 0, 0, 0);
    }
#pragma unroll
    for (int i = 0; i < 4; ++i)
#pragma unroll
      for (int j = 0; j < 4; ++j)
#pragma unroll
        for (int r = 0; r < 4; ++r)
          Sb[(size_t)task * (Kk * Vv) + (size_t)(w * 64 + i * 16 + fq * 4 + r) * Vv +
             vb4 * 64 + j * 16 + fr] = f2b(acc[i][j][r]);
  }
}

// ---------------- passR: sequential chunk recombine; 64k x 32v tiles (256 blocks) ----
__global__ __launch_bounds__(256) void passR_kernel(
    const unsigned short* __restrict__ Sb, const float* __restrict__ Dendb,
    unsigned short* __restrict__ S0Tb, float* __restrict__ state_out) {
  const int vt = blockIdx.x, kt = blockIdx.y, b = blockIdx.z;  // (8, 4, 8)
  const int tid = threadIdx.x;
  const int kq = tid >> 2;     // k_local 0..63
  const int vq = tid & 3;      // v group (8 v each)
  const int vr = tid >> 3;     // write-phase: v row 0..31
  const int kqq = tid & 7;     // write-phase: k group (8 k each)
  __shared__ __align__(16) unsigned short Ts[32][72];
  float st[8];
#pragma unroll
  for (int j = 0; j < 8; ++j) st[j] = 0.f;
  for (int c = 0; c < NC; ++c) {
    const int task = b * NC + c;
#pragma unroll
    for (int j = 0; j < 8; ++j) Ts[vq * 8 + j][kq] = f2b(st[j]);
    __syncthreads();
    {
      unsigned short* dst = S0Tb + (size_t)task * (Kk * Vv) +
                            (size_t)(vt * 32 + vr) * Kk + kt * 64 + kqq * 8;
      *(uint4*)dst = *(const uint4*)&Ts[vr][kqq * 8];
    }
    __syncthreads();
    const float d = Dendb[task * 256 + kt * 64 + kq];
    const unsigned short* sp = Sb + (size_t)task * (Kk * Vv) +
                               (size_t)(kt * 64 + kq) * Vv + vt * 32 + vq * 8;
    uint4 raw = *(const uint4*)sp;
    unsigned ws_[4] = {raw.x, raw.y, raw.z, raw.w};
#pragma unroll
    for (int e = 0; e < 4; ++e) {
      float lo = __uint_as_float(ws_[e] << 16);
      float hi = __uint_as_float(ws_[e] & 0xFFFF0000u);
      st[e * 2]     = d * st[e * 2] + lo;
      st[e * 2 + 1] = d * st[e * 2 + 1] + hi;
    }
  }
  float* so = state_out + (size_t)(b * Kk + kt * 64 + kq) * Vv + vt * 32 + vq * 8;
#pragma unroll
  for (int j = 0; j < 8; ++j) so[j] = st[j];
}

// ---------------- passO: per (b,c): att = q2*S0 + tril(A)*v ----------------
__global__ __launch_bounds__(256) void passO_kernel(
    const unsigned short* __restrict__ qab, const unsigned short* __restrict__ kab,
    const unsigned short* __restrict__ q2b, const float* __restrict__ LBb,
    const unsigned short* __restrict__ S0Tb, const unsigned short* __restrict__ vTb,
    unsigned short* __restrict__ attb) {
  const int c = blockIdx.x, b = blockIdx.y;
  const int task = b * NC + c;
  const int tid = threadIdx.x, lane = tid & 63, w = tid >> 6;
  const int fr = lane & 15, fq = lane >> 4, fk = fq * 8;
  __shared__ float LB_s[4][256];
  __shared__ float D_s[6][256];   // pair (I>J) scale factors: pidx = I*(I-1)/2 + J
  __shared__ __align__(16) unsigned short A_s[64][72];
  const size_t tbase = (size_t)task * (CC * Kk);
  for (int idx = tid; idx < 1024; idx += 256) LB_s[idx >> 8][idx & 255] = LBb[(size_t)task * 1024 + idx];
  for (int idx = tid; idx < 64 * 72 / 2; idx += 256) ((unsigned*)A_s)[idx] = 0;
  __syncthreads();
  // precompute pair scales (value depends only on k -> compute once, not per-lane-row)
  {
    const int kk = tid;
#pragma unroll
    for (int pi = 0; pi < 6; ++pi) {
      const int I = (pi >= 3) ? 3 : (pi >= 1) ? 2 : 1;
      const int J = pi - (I * (I - 1)) / 2;
      D_s[pi][kk] = exp2f(LB_s[I][kk] - LB_s[J][kk]);
    }
  }
  __syncthreads();
  for (int p = w; p < 10; p += 4) {
    const int I = (p >= 6) ? 3 : (p >= 3) ? 2 : (p >= 1) ? 1 : 0;
    const int J = p - (I * (I + 1)) / 2;
    const int pidx = (I * (I - 1)) / 2 + J;  // valid when I != J
    f32x4 acc = {0.f, 0.f, 0.f, 0.f};
#pragma unroll
    for (int ks = 0; ks < 8; ++ks) {
      const int k0 = ks * 32 + fk;
      bf16x8 af = *(const bf16x8*)(qab + tbase + (size_t)(I * 16 + fr) * Kk + k0);
      if (I != J) {
#pragma unroll
        for (int e = 0; e < 8; ++e)
          af[e] = (__bf16)((float)af[e] * D_s[pidx][k0 + e]);
      }
      bf16x8 bf = *(const bf16x8*)(kab + tbase + (size_t)(J * 16 + fr) * Kk + k0);
      acc = __builtin_amdgcn_mfma_f32_16x16x32_bf16(af, bf, acc, 0, 0, 0);
    }
#pragma unroll
    for (int r = 0; r < 4; ++r) {
      const int ml = fq * 4 + r, nl = fr;
      bool keep = (I != J) || (nl <= ml);
      A_s[I * 16 + ml][J * 16 + nl] = keep ? f2b(acc[r]) : (unsigned short)0;
    }
  }
  __syncthreads();
  f32x4 acc2[4][4] = {};
  const unsigned short* q2t = q2b + tbase;
  const unsigned short* s0t = S0Tb + (size_t)task * (Kk * Vv);
  const unsigned short* vtp = vTb + (size_t)b * (Vv * Tt) + (size_t)c * CC;
  const int vbase = w * 64;
#pragma unroll
  for (int ks = 0; ks < 8; ++ks) {
    const int k0 = ks * 32 + fk;
    bf16x8 af[4], bf[4];
#pragma unroll
    for (int i = 0; i < 4; ++i) af[i] = *(const bf16x8*)(q2t + (size_t)(i * 16 + fr) * Kk + k0);
#pragma unroll
    for (int j = 0; j < 4; ++j) bf[j] = *(const bf16x8*)(s0t + (size_t)(vbase + j * 16 + fr) * Kk + k0);
#pragma unroll
    for (int i = 0; i < 4; ++i)
#pragma unroll
      for (int j = 0; j < 4; ++j)
        acc2[i][j] = __builtin_amdgcn_mfma_f32_16x16x32_bf16(af[i], bf[j], acc2[i][j], 0, 0, 0);
  }
#pragma unroll
  for (int ks = 0; ks < 2; ++ks) {
    const int s0 = ks * 32 + fk;
    bf16x8 af[4], bf[4];
#pragma unroll
    for (int i = 0; i < 4; ++i) af[i] = *(const bf16x8*)&A_s[i * 16 + fr][s0];
#pragma unroll
    for (int j = 0; j < 4; ++j) bf[j] = *(const bf16x8*)(vtp + (size_t)(vbase + j * 16 + fr) * Tt + s0);
#pragma unroll
    for (int i = 0; i < 4; ++i)
#pragma unroll
      for (int j = 0; j < 4; ++j)
        acc2[i][j] = __builtin_amdgcn_mfma_f32_16x16x32_bf16(af[i], bf[j], acc2[i][j], 0, 0, 0);
  }
#pragma unroll
  for (int i = 0; i < 4; ++i)
#pragma unroll
    for (int j = 0; j < 4; ++j)
#pragma unroll
      for (int r = 0; r < 4; ++r)
        attb[((size_t)b * Tt + c * CC + i * 16 + fq * 4 + r) * Vv + vbase + j * 16 + fr]
            = f2b(acc2[i][j][r]);
}

extern "C" void kernel_launch(void* const* d_in, const int* in_sizes, int n_in,
                              void* d_out, int out_size, void* d_ws, size_t ws_size,
                              hipStream_t stream) {
  const float* hs = (const float*)d_in[0];
  const float* Wq = (const float*)d_in[1];
  const float* bq = (const float*)d_in[2];
  const float* Wk = (const float*)d_in[3];
  const float* bk = (const float*)d_in[4];
  const float* Wv = (const float*)d_in[5];
  const float* bv = (const float*)d_in[6];
  const float* Wg = (const float*)d_in[7];
  const float* bg = (const float*)d_in[8];
  const float* Wo = (const float*)d_in[9];
  const float* bo = (const float*)d_in[10];

  float* out = (float*)d_out;
  float* state_out = out + (size_t)Bb * Tt * Oo;

  char* p = (char*)d_ws;
  auto alloc = [&](size_t bytes) {
    char* r = p;
    p += (bytes + 255) & ~(size_t)255;
    return r;
  };
  unsigned short* hsb   = (unsigned short*)alloc((size_t)Bb * Tt * Hh * 2);   // 32MB
  unsigned short* WallT = (unsigned short*)alloc((size_t)1024 * Hh * 2);      // 2MB
  unsigned short* WoT   = (unsigned short*)alloc((size_t)Oo * Vv * 2);
  unsigned short* qb    = (unsigned short*)alloc((size_t)Bb * Tt * Kk * 2);   // 8MB each
  unsigned short* kb    = (unsigned short*)alloc((size_t)Bb * Tt * Kk * 2);
  unsigned short* lgb   = (unsigned short*)alloc((size_t)Bb * Tt * Kk * 2);   // f16
  unsigned short* vb    = (unsigned short*)alloc((size_t)Bb * Tt * Vv * 2);
  unsigned short* vTb   = (unsigned short*)alloc((size_t)Bb * Vv * Tt * 2);
  unsigned short* attb  = (unsigned short*)alloc((size_t)Bb * Tt * Vv * 2);
  unsigned short* q2b   = (unsigned short*)alloc((size_t)Bb * Tt * Kk * 2);
  unsigned short* qab   = (unsigned short*)alloc((size_t)Bb * Tt * Kk * 2);
  unsigned short* kab   = (unsigned short*)alloc((size_t)Bb * Tt * Kk * 2);
  float*          LBb   = (float*)alloc((size_t)Bb * NC * 4 * Kk * 4);
  float*          Dendb = (float*)alloc((size_t)Bb * NC * Kk * 4);
  unsigned short* Sb    = (unsigned short*)alloc((size_t)Bb * NC * Kk * Vv * 2);  // 32MB
  unsigned short* S0Tb  = (unsigned short*)alloc((size_t)Bb * NC * Kk * Vv * 2);  // 32MB

  // 1) casts + weight transposes (concat projection weights into WallT rows)
  int n4 = Bb * Tt * Hh / 4;
  cast_bf16_kernel<<<(n4 + 255) / 256, 256, 0, stream>>>(hs, hsb, n4);
  transpose_cast_kernel<<<dim3(Hh / 32, Kk / 32), 256, 0, stream>>>(Wq, WallT + 0 * Kk * Hh, Hh, Kk);
  transpose_cast_kernel<<<dim3(Hh / 32, Kk / 32), 256, 0, stream>>>(Wk, WallT + 1 * Kk * Hh, Hh, Kk);
  transpose_cast_kernel<<<dim3(Hh / 32, Kk / 32), 256, 0, stream>>>(Wg, WallT + 2 * Kk * Hh, Hh, Kk);
  transpose_cast_kernel<<<dim3(Hh / 32, Kk / 32), 256, 0, stream>>>(Wv, WallT + 3 * Kk * Hh, Hh, Kk);
  transpose_cast_kernel<<<dim3(Vv / 32, Oo / 32), 256, 0, stream>>>(Wo, WoT, Vv, Oo);

  // 2) fused projections: one 128^2-tile GEMM, N=1024 (grid 1024 blocks, 4/CU)
  gemm_mf_kernel<0><<<dim3(1024 / BN, (Bb * Tt) / BM), 256, 0, stream>>>(
      hsb, WallT, bq, bk, bg, bv, nullptr, qb, kb, lgb, vb, Bb * Tt, 1024, Hh);

  // 3) vT: per-batch transpose (T x V -> V x T)
  transpose_b16_kernel<<<dim3(Tt / 32, Vv / 32, Bb), 256, 0, stream>>>(vb, vTb, Tt, Vv);

  // 4) fused prep + per-chunk state GEMM
  prep_sgemm_kernel<<<dim3(NC, Bb), 256, 0, stream>>>(qb, kb, lgb, vTb, q2b, qab, kab,
                                                      LBb, Dendb, Sb);

  // 5) sequential chunk recombine -> S0T (pre-chunk states) + final state
  passR_kernel<<<dim3(Vv / 32, Kk / 64, Bb), 256, 0, stream>>>(Sb, Dendb, S0Tb, state_out);

  // 6) outputs: att = q2.S0 + tril(A).v
  passO_kernel<<<dim3(NC, Bb), 256, 0, stream>>>(qab, kab, q2b, LBb, S0Tb, vTb, attb);

  // 7) output projection: pipelined 128^2 kernel, f32 out (grid 1024 blocks, 4/CU)
  gemm_mf_kernel<1><<<dim3(Oo / BN, (Bb * Tt) / BM), 256, 0, stream>>>(
      attb, WoT, bo, nullptr, nullptr, nullptr, out, nullptr, nullptr, nullptr, nullptr,
      Bb * Tt, Oo, Vv);
}

// Round 10
// 218.616 us; speedup vs baseline: 1.5339x; 1.0973x over previous
//
#include <hip/hip_runtime.h>

// Problem dims (fixed by setup_inputs)
#define Bb 8
#define Tt 2048
#define Hh 1024
#define Kk 256
#define Vv 256
#define Oo 1024
#define CC 64   // chunk length
#define NC 32   // chunks per batch (Tt/CC)

typedef __attribute__((ext_vector_type(8))) __bf16 bf16x8;
typedef __attribute__((ext_vector_type(4))) float f32x4;

__device__ __forceinline__ unsigned short f2b(float f) {
  unsigned u = __float_as_uint(f);
  u = (u + 0x7FFFu + ((u >> 16) & 1u)) >> 16;
  return (unsigned short)u;
}
__device__ __forceinline__ float b2f(unsigned short u) {
  return __uint_as_float(((unsigned)u) << 16);
}
__device__ __forceinline__ void gload_lds16(const unsigned short* g, unsigned short* l) {
  __builtin_amdgcn_global_load_lds(
      (const __attribute__((address_space(1))) void*)g,
      (__attribute__((address_space(3))) void*)l, 16, 0, 0);
}

// ---------------- cast f32 -> bf16 (vectorized) ----------------
__global__ __launch_bounds__(256) void cast_bf16_kernel(const float* __restrict__ in,
                                                        unsigned short* __restrict__ out,
                                                        int n4) {
  int i = blockIdx.x * 256 + threadIdx.x;
  if (i >= n4) return;
  float4 v = ((const float4*)in)[i];
  ushort4 o;
  o.x = f2b(v.x); o.y = f2b(v.y); o.z = f2b(v.z); o.w = f2b(v.w);
  ((ushort4*)out)[i] = o;
}

// ---------------- transpose + cast: W (H x N) f32 -> WT (N x H) bf16 ----------------
__global__ __launch_bounds__(256) void transpose_cast_kernel(const float* __restrict__ W,
                                                             unsigned short* __restrict__ WT,
                                                             int H, int N) {
  __shared__ float tile[32][33];
  int h0 = blockIdx.x * 32, n0 = blockIdx.y * 32;
  int tx = threadIdx.x & 31, ty = threadIdx.x >> 5;
  for (int r = ty; r < 32; r += 8)
    tile[r][tx] = W[(size_t)(h0 + r) * N + n0 + tx];
  __syncthreads();
  for (int r = ty; r < 32; r += 8)
    WT[(size_t)(n0 + r) * H + h0 + tx] = f2b(tile[tx][r]);
}

// ---------------- GEMM: 128x128, BK=64, 4 waves, swizzled LDS, 4 blocks/CU ----
// C = A (MxK) * Bt^T
// MODE 0: proj epilogue (LDS-staged coalesced writes; v-panel written transposed to vT)
// MODE 1: f32 out + bias b0p
#define BM 128
#define BN 128
#define BK 64

template <int MODE>
__global__ __launch_bounds__(256, 4) void gemm_mf_kernel(
    const unsigned short* __restrict__ A, const unsigned short* __restrict__ Bt,
    const float* __restrict__ b0p, const float* __restrict__ b1p,
    const float* __restrict__ b2p, const float* __restrict__ b3p,
    float* __restrict__ Cf,
    unsigned short* __restrict__ O0, unsigned short* __restrict__ O1,
    unsigned short* __restrict__ O2, unsigned short* __restrict__ O3,
    int M, int N, int K) {
  // One 32 KiB LDS pool: As/Bs during the K loop, reused as the epilogue stage tile.
  __shared__ __align__(16) unsigned short shbuf[16384];
  unsigned short* As = shbuf;          // 128*64
  unsigned short* Bs = shbuf + 8192;   // 128*64
  const int tid = threadIdx.x;
  const int lane = tid & 63, wid = tid >> 6;        // 4 waves
  const int wm = wid >> 1, wn = wid & 1;            // 2x2 wave grid; wave = 64x64 out
  // XCD-LOCAL tile mapping: XCD (lin&7) owns gridY/8 consecutive m-panels; n fastest.
  // The 8 n-tiles sharing an A-panel run concurrently on the SAME XCD -> A-panel
  // crosses L3 once, re-reads hit that XCD's L2.
  const int lin = blockIdx.x + blockIdx.y * gridDim.x;
  const int xcd = lin & 7;
  const int jj = lin >> 3;
  const int mpg = gridDim.y >> 3;                   // m-panels per XCD
  const int m0 = (xcd * mpg + jj / gridDim.x) * BM;
  const int n0 = (jj % gridDim.x) * BN;
  const int fr = lane & 15, fq = lane >> 4;
  // staging: per gload a wave writes 8 rows x 128B. Lane l -> row +(l>>3),
  // LDS 16B-chunk (l&7); global source chunk = (l&7) ^ (l>>3).
  const int srl = lane >> 3;
  const int scs = ((lane & 7) ^ srl) * 8;
  const unsigned short* gaBase = A + (size_t)(m0 + srl) * K + scs;
  const unsigned short* gbBase = Bt + (size_t)(n0 + srl) * K + scs;

  f32x4 acc[4][4] = {};
  const int nt = K / BK;
  for (int t = 0; t < nt; ++t) {
    const int k0 = t * BK;
    __syncthreads();  // previous iter's LDS reads done
#pragma unroll
    for (int inst = 0; inst < 4; ++inst) {
      const int rb = wid * 32 + inst * 8;
      gload_lds16(gaBase + (size_t)rb * K + k0, &As[rb * BK]);
      gload_lds16(gbBase + (size_t)rb * K + k0, &Bs[rb * BK]);
    }
    __syncthreads();  // staged data visible (drain hidden by co-resident blocks)
#pragma unroll
    for (int ks = 0; ks < 2; ++ks) {
      bf16x8 af[4], bfv[4];
#pragma unroll
      for (int j = 0; j < 4; ++j) {
        const int R = wn * 64 + j * 16 + fr;
        const int ch = ((ks << 2) | fq) ^ (fr & 7);
        bfv[j] = *(const bf16x8*)&Bs[R * BK + ch * 8];
      }
#pragma unroll
      for (int i = 0; i < 4; ++i) {
        const int R = wm * 64 + i * 16 + fr;
        const int ch = ((ks << 2) | fq) ^ (fr & 7);
        af[i] = *(const bf16x8*)&As[R * BK + ch * 8];
      }
#pragma unroll
      for (int i = 0; i < 4; ++i)
#pragma unroll
        for (int j = 0; j < 4; ++j)
          acc[i][j] = __builtin_amdgcn_mfma_f32_16x16x32_bf16(af[i], bfv[j], acc[i][j], 0, 0, 0);
    }
  }
  if (MODE == 1) {
    // simple epilogue: f32, 64B segments per 16-lane cluster (no amplification)
#pragma unroll
    for (int j = 0; j < 4; ++j) {
      const int n = n0 + wn * 64 + j * 16 + fr;
      const float bv = b0p[n];
#pragma unroll
      for (int i = 0; i < 4; ++i) {
        const int mb = m0 + wm * 64 + i * 16 + fq * 4;
#pragma unroll
        for (int r = 0; r < 4; ++r)
          Cf[(size_t)(mb + r) * N + n] = acc[i][j][r] + bv;
      }
    }
  } else {
    // LDS-staged epilogue: transform in reg, stage bf16/f16 tile (XOR-chunk swizzle),
    // then write 256B-contiguous rows with dwordx4 (kills 2x write amplification).
    __syncthreads();  // all waves done reading As/Bs before reuse
    const int sel = n0 >> 8;
    const float* bp = sel == 0 ? b0p : sel == 1 ? b1p : sel == 2 ? b2p : b3p;
#pragma unroll
    for (int j = 0; j < 4; ++j) {
      const int ncol = wn * 64 + j * 16 + fr;       // tile-local col [0,128)
      const int nloc = (n0 & 255) + ncol;           // panel-local col [0,256)
      const float bv = bp[nloc];
#pragma unroll
      for (int i = 0; i < 4; ++i) {
#pragma unroll
        for (int r = 0; r < 4; ++r) {
          const int ml = wm * 64 + i * 16 + fq * 4 + r;
          const float x = acc[i][j][r] + bv;
          unsigned short us;
          if (sel == 0) {
            us = f2b(x);
          } else if (sel == 1) {
            us = f2b(1.f / (1.f + expf(-x)));
          } else if (sel == 2) {
            float e = exp2f(-x * 1.44269504f);
            float lg = -log2f(1.f + e);
            _Float16 hv = (_Float16)lg;
            __builtin_memcpy(&us, &hv, 2);
          } else {
            us = f2b(x);
          }
          if (sel == 3) {  // stage transposed: row = v (ncol), col = t (ml)
            const int cm = (ml >> 3) ^ (ncol & 15);
            shbuf[ncol * 128 + cm * 8 + (ml & 7)] = us;
          } else {         // row = m (ml), col = n (ncol)
            const int cn = (ncol >> 3) ^ (ml & 15);
            shbuf[ml * 128 + cn * 8 + (ncol & 7)] = us;
          }
        }
      }
    }
    __syncthreads();
    // write out: 128 rows x 256B; 2 threads/row, 8 x 16B stores each
    const int row = tid >> 1;
    const int half = tid & 1;
    if (sel == 3) {
      unsigned short* dst = O3 + ((size_t)(m0 >> 11) * Vv + (n0 & 255) + row) * Tt +
                            (m0 & 2047) + half * 64;
#pragma unroll
      for (int ic = 0; ic < 8; ++ic) {
        const int chunk = half * 8 + ic;
        const int sc = chunk ^ (row & 15);
        *(uint4*)(dst + ic * 8) = *(const uint4*)&shbuf[row * 128 + sc * 8];
      }
    } else {
      unsigned short* Op = sel == 0 ? O0 : sel == 1 ? O1 : O2;
      unsigned short* dst = Op + (size_t)(m0 + row) * 256 + (n0 & 255) + half * 64;
#pragma unroll
      for (int ic = 0; ic < 8; ++ic) {
        const int chunk = half * 8 + ic;
        const int sc = chunk ^ (row & 15);
        *(uint4*)(dst + ic * 8) = *(const uint4*)&shbuf[row * 128 + sc * 8];
      }
    }
  }
}

// ---------------- fused prep+sgemm: per (b,c) task ----------------
__global__ __launch_bounds__(256) void prep_sgemm_kernel(
    const unsigned short* __restrict__ qb, const unsigned short* __restrict__ kb,
    const unsigned short* __restrict__ lgb, const unsigned short* __restrict__ vTb,
    unsigned short* __restrict__ q2b, unsigned short* __restrict__ qab,
    unsigned short* __restrict__ kab,
    float* __restrict__ LBb, float* __restrict__ Dendb,
    unsigned short* __restrict__ Sb) {
  __shared__ __align__(16) unsigned short khs[256][72];
  const int c = blockIdx.x, b = blockIdx.y;
  const int k = threadIdx.x;
  const int task = b * NC + c;
  const size_t rowbase = ((size_t)b * Tt + (size_t)c * CC) * Kk + k;
  float Ls = 0.f;
  float LBr[4];
#pragma unroll
  for (int gq = 0; gq < 4; ++gq) {
    LBr[gq] = Ls;
#pragma unroll
    for (int tt = 0; tt < 16; ++tt) {
      int t = gq * 16 + tt;
      _Float16 hv;
      __builtin_memcpy(&hv, &lgb[rowbase + (size_t)t * Kk], 2);
      Ls += (float)hv;
    }
  }
  const float Lend = Ls;
#pragma unroll
  for (int gq = 0; gq < 4; ++gq) LBb[(size_t)task * 1024 + gq * 256 + k] = LBr[gq];
  Dendb[task * 256 + k] = exp2f(Lend);
  float L = 0.f;
#pragma unroll
  for (int gq = 0; gq < 4; ++gq) {
    const float LBc = LBr[gq];
    unsigned kw[8];
#pragma unroll
    for (int tt = 0; tt < 16; ++tt) {
      int t = gq * 16 + tt;
      size_t off = rowbase + (size_t)t * Kk;
      _Float16 hv;
      __builtin_memcpy(&hv, &lgb[off], 2);
      L += (float)hv;
      float qv = b2f(qb[off]);
      float kv = b2f(kb[off]);
      q2b[off] = f2b(qv * exp2f(L));
      qab[off] = f2b(qv * exp2f(L - LBc));
      kab[off] = f2b(kv * exp2f(LBc - L));
      unsigned short kh = f2b(kv * exp2f(Lend - L));
      if (tt & 1) kw[tt >> 1] |= ((unsigned)kh) << 16;
      else        kw[tt >> 1] = kh;
    }
    uint4 u0; u0.x = kw[0]; u0.y = kw[1]; u0.z = kw[2]; u0.w = kw[3];
    uint4 u1; u1.x = kw[4]; u1.y = kw[5]; u1.z = kw[6]; u1.w = kw[7];
    *(uint4*)&khs[k][gq * 16] = u0;
    *(uint4*)&khs[k][gq * 16 + 8] = u1;
  }
  __syncthreads();
  const int tid = threadIdx.x, lane = tid & 63, w = tid >> 6;
  const int fr = lane & 15, fq = lane >> 4, fk = fq * 8;
  const unsigned short* vt = vTb + (size_t)b * (Vv * Tt) + (size_t)c * CC;
  for (int vb4 = 0; vb4 < 4; ++vb4) {
    f32x4 acc[4][4] = {};
#pragma unroll
    for (int ks = 0; ks < 2; ++ks) {
      bf16x8 af[4], bf[4];
#pragma unroll
      for (int i = 0; i < 4; ++i)
        af[i] = *(const bf16x8*)&khs[w * 64 + i * 16 + fr][ks * 32 + fk];
#pragma unroll
      for (int j = 0; j < 4; ++j)
        bf[j] = *(const bf16x8*)(vt + (size_t)(vb4 * 64 + j * 16 + fr) * Tt + ks * 32 + fk);
#pragma unroll
      for (int i = 0; i < 4; ++i)
#pragma unroll
        for (int j = 0; j < 4; ++j)
          acc[i][j] = __builtin_amdgcn_mfma_f32_16x16x32_bf16(af[i], bf[j], acc[i][j], 0, 0, 0);
    }
#pragma unroll
    for (int i = 0; i < 4; ++i)
#pragma unroll
      for (int j = 0; j < 4; ++j)
#pragma unroll
        for (int r = 0; r < 4; ++r)
          Sb[(size_t)task * (Kk * Vv) + (size_t)(w * 64 + i * 16 + fq * 4 + r) * Vv +
             vb4 * 64 + j * 16 + fr] = f2b(acc[i][j][r]);
  }
}

// ---------------- passR: sequential chunk recombine; 64k x 32v tiles (256 blocks) ----
__global__ __launch_bounds__(256) void passR_kernel(
    const unsigned short* __restrict__ Sb, const float* __restrict__ Dendb,
    unsigned short* __restrict__ S0Tb, float* __restrict__ state_out) {
  const int vt = blockIdx.x, kt = blockIdx.y, b = blockIdx.z;  // (8, 4, 8)
  const int tid = threadIdx.x;
  const int kq = tid >> 2;     // k_local 0..63
  const int vq = tid & 3;      // v group (8 v each)
  const int vr = tid >> 3;     // write-phase: v row 0..31
  const int kqq = tid & 7;     // write-phase: k group (8 k each)
  __shared__ __align__(16) unsigned short Ts[32][72];
  float st[8];
#pragma unroll
  for (int j = 0; j < 8; ++j) st[j] = 0.f;
  for (int c = 0; c < NC; ++c) {
    const int task = b * NC + c;
#pragma unroll
    for (int j = 0; j < 8; ++j) Ts[vq * 8 + j][kq] = f2b(st[j]);
    __syncthreads();
    {
      unsigned short* dst = S0Tb + (size_t)task * (Kk * Vv) +
                            (size_t)(vt * 32 + vr) * Kk + kt * 64 + kqq * 8;
      *(uint4*)dst = *(const uint4*)&Ts[vr][kqq * 8];
    }
    __syncthreads();
    const float d = Dendb[task * 256 + kt * 64 + kq];
    const unsigned short* sp = Sb + (size_t)task * (Kk * Vv) +
                               (size_t)(kt * 64 + kq) * Vv + vt * 32 + vq * 8;
    uint4 raw = *(const uint4*)sp;
    unsigned ws_[4] = {raw.x, raw.y, raw.z, raw.w};
#pragma unroll
    for (int e = 0; e < 4; ++e) {
      float lo = __uint_as_float(ws_[e] << 16);
      float hi = __uint_as_float(ws_[e] & 0xFFFF0000u);
      st[e * 2]     = d * st[e * 2] + lo;
      st[e * 2 + 1] = d * st[e * 2 + 1] + hi;
    }
  }
  float* so = state_out + (size_t)(b * Kk + kt * 64 + kq) * Vv + vt * 32 + vq * 8;
#pragma unroll
  for (int j = 0; j < 8; ++j) so[j] = st[j];
}

// ---------------- passO: per (b,c): att = q2*S0 + tril(A)*v ----------------
__global__ __launch_bounds__(256) void passO_kernel(
    const unsigned short* __restrict__ qab, const unsigned short* __restrict__ kab,
    const unsigned short* __restrict__ q2b, const float* __restrict__ LBb,
    const unsigned short* __restrict__ S0Tb, const unsigned short* __restrict__ vTb,
    unsigned short* __restrict__ attb) {
  const int c = blockIdx.x, b = blockIdx.y;
  const int task = b * NC + c;
  const int tid = threadIdx.x, lane = tid & 63, w = tid >> 6;
  const int fr = lane & 15, fq = lane >> 4, fk = fq * 8;
  __shared__ float LB_s[4][256];
  __shared__ float D_s[6][256];   // pair (I>J) scale factors: pidx = I*(I-1)/2 + J
  __shared__ __align__(16) unsigned short A_s[64][72];
  const size_t tbase = (size_t)task * (CC * Kk);
  for (int idx = tid; idx < 1024; idx += 256) LB_s[idx >> 8][idx & 255] = LBb[(size_t)task * 1024 + idx];
  for (int idx = tid; idx < 64 * 72 / 2; idx += 256) ((unsigned*)A_s)[idx] = 0;
  __syncthreads();
  {
    const int kk = tid;
#pragma unroll
    for (int pi = 0; pi < 6; ++pi) {
      const int I = (pi >= 3) ? 3 : (pi >= 1) ? 2 : 1;
      const int J = pi - (I * (I - 1)) / 2;
      D_s[pi][kk] = exp2f(LB_s[I][kk] - LB_s[J][kk]);
    }
  }
  __syncthreads();
  for (int p = w; p < 10; p += 4) {
    const int I = (p >= 6) ? 3 : (p >= 3) ? 2 : (p >= 1) ? 1 : 0;
    const int J = p - (I * (I + 1)) / 2;
    const int pidx = (I * (I - 1)) / 2 + J;  // valid when I != J
    f32x4 acc = {0.f, 0.f, 0.f, 0.f};
#pragma unroll
    for (int ks = 0; ks < 8; ++ks) {
      const int k0 = ks * 32 + fk;
      bf16x8 af = *(const bf16x8*)(qab + tbase + (size_t)(I * 16 + fr) * Kk + k0);
      if (I != J) {
#pragma unroll
        for (int e = 0; e < 8; ++e)
          af[e] = (__bf16)((float)af[e] * D_s[pidx][k0 + e]);
      }
      bf16x8 bf = *(const bf16x8*)(kab + tbase + (size_t)(J * 16 + fr) * Kk + k0);
      acc = __builtin_amdgcn_mfma_f32_16x16x32_bf16(af, bf, acc, 0, 0, 0);
    }
#pragma unroll
    for (int r = 0; r < 4; ++r) {
      const int ml = fq * 4 + r, nl = fr;
      bool keep = (I != J) || (nl <= ml);
      A_s[I * 16 + ml][J * 16 + nl] = keep ? f2b(acc[r]) : (unsigned short)0;
    }
  }
  __syncthreads();
  f32x4 acc2[4][4] = {};
  const unsigned short* q2t = q2b + tbase;
  const unsigned short* s0t = S0Tb + (size_t)task * (Kk * Vv);
  const unsigned short* vtp = vTb + (size_t)b * (Vv * Tt) + (size_t)c * CC;
  const int vbase = w * 64;
#pragma unroll
  for (int ks = 0; ks < 8; ++ks) {
    const int k0 = ks * 32 + fk;
    bf16x8 af[4], bf[4];
#pragma unroll
    for (int i = 0; i < 4; ++i) af[i] = *(const bf16x8*)(q2t + (size_t)(i * 16 + fr) * Kk + k0);
#pragma unroll
    for (int j = 0; j < 4; ++j) bf[j] = *(const bf16x8*)(s0t + (size_t)(vbase + j * 16 + fr) * Kk + k0);
#pragma unroll
    for (int i = 0; i < 4; ++i)
#pragma unroll
      for (int j = 0; j < 4; ++j)
        acc2[i][j] = __builtin_amdgcn_mfma_f32_16x16x32_bf16(af[i], bf[j], acc2[i][j], 0, 0, 0);
  }
#pragma unroll
  for (int ks = 0; ks < 2; ++ks) {
    const int s0 = ks * 32 + fk;
    bf16x8 af[4], bf[4];
#pragma unroll
    for (int i = 0; i < 4; ++i) af[i] = *(const bf16x8*)&A_s[i * 16 + fr][s0];
#pragma unroll
    for (int j = 0; j < 4; ++j) bf[j] = *(const bf16x8*)(vtp + (size_t)(vbase + j * 16 + fr) * Tt + s0);
#pragma unroll
    for (int i = 0; i < 4; ++i)
#pragma unroll
      for (int j = 0; j < 4; ++j)
        acc2[i][j] = __builtin_amdgcn_mfma_f32_16x16x32_bf16(af[i], bf[j], acc2[i][j], 0, 0, 0);
  }
#pragma unroll
  for (int i = 0; i < 4; ++i)
#pragma unroll
    for (int j = 0; j < 4; ++j)
#pragma unroll
      for (int r = 0; r < 4; ++r)
        attb[((size_t)b * Tt + c * CC + i * 16 + fq * 4 + r) * Vv + vbase + j * 16 + fr]
            = f2b(acc2[i][j][r]);
}

extern "C" void kernel_launch(void* const* d_in, const int* in_sizes, int n_in,
                              void* d_out, int out_size, void* d_ws, size_t ws_size,
                              hipStream_t stream) {
  const float* hs = (const float*)d_in[0];
  const float* Wq = (const float*)d_in[1];
  const float* bq = (const float*)d_in[2];
  const float* Wk = (const float*)d_in[3];
  const float* bk = (const float*)d_in[4];
  const float* Wv = (const float*)d_in[5];
  const float* bv = (const float*)d_in[6];
  const float* Wg = (const float*)d_in[7];
  const float* bg = (const float*)d_in[8];
  const float* Wo = (const float*)d_in[9];
  const float* bo = (const float*)d_in[10];

  float* out = (float*)d_out;
  float* state_out = out + (size_t)Bb * Tt * Oo;

  char* p = (char*)d_ws;
  auto alloc = [&](size_t bytes) {
    char* r = p;
    p += (bytes + 255) & ~(size_t)255;
    return r;
  };
  unsigned short* hsb   = (unsigned short*)alloc((size_t)Bb * Tt * Hh * 2);   // 32MB
  unsigned short* WallT = (unsigned short*)alloc((size_t)1024 * Hh * 2);      // 2MB
  unsigned short* WoT   = (unsigned short*)alloc((size_t)Oo * Vv * 2);
  unsigned short* qb    = (unsigned short*)alloc((size_t)Bb * Tt * Kk * 2);   // 8MB each
  unsigned short* kb    = (unsigned short*)alloc((size_t)Bb * Tt * Kk * 2);
  unsigned short* lgb   = (unsigned short*)alloc((size_t)Bb * Tt * Kk * 2);   // f16
  unsigned short* vTb   = (unsigned short*)alloc((size_t)Bb * Vv * Tt * 2);
  unsigned short* attb  = (unsigned short*)alloc((size_t)Bb * Tt * Vv * 2);
  unsigned short* q2b   = (unsigned short*)alloc((size_t)Bb * Tt * Kk * 2);
  unsigned short* qab   = (unsigned short*)alloc((size_t)Bb * Tt * Kk * 2);
  unsigned short* kab   = (unsigned short*)alloc((size_t)Bb * Tt * Kk * 2);
  float*          LBb   = (float*)alloc((size_t)Bb * NC * 4 * Kk * 4);
  float*          Dendb = (float*)alloc((size_t)Bb * NC * Kk * 4);
  unsigned short* Sb    = (unsigned short*)alloc((size_t)Bb * NC * Kk * Vv * 2);  // 32MB
  unsigned short* S0Tb  = (unsigned short*)alloc((size_t)Bb * NC * Kk * Vv * 2);  // 32MB

  // 1) casts + weight transposes (concat projection weights into WallT rows)
  int n4 = Bb * Tt * Hh / 4;
  cast_bf16_kernel<<<(n4 + 255) / 256, 256, 0, stream>>>(hs, hsb, n4);
  transpose_cast_kernel<<<dim3(Hh / 32, Kk / 32), 256, 0, stream>>>(Wq, WallT + 0 * Kk * Hh, Hh, Kk);
  transpose_cast_kernel<<<dim3(Hh / 32, Kk / 32), 256, 0, stream>>>(Wk, WallT + 1 * Kk * Hh, Hh, Kk);
  transpose_cast_kernel<<<dim3(Hh / 32, Kk / 32), 256, 0, stream>>>(Wg, WallT + 2 * Kk * Hh, Hh, Kk);
  transpose_cast_kernel<<<dim3(Hh / 32, Kk / 32), 256, 0, stream>>>(Wv, WallT + 3 * Kk * Hh, Hh, Kk);
  transpose_cast_kernel<<<dim3(Vv / 32, Oo / 32), 256, 0, stream>>>(Wo, WoT, Vv, Oo);

  // 2) fused projections: 128^2 tiles, N=1024; v written directly transposed to vT
  gemm_mf_kernel<0><<<dim3(1024 / BN, (Bb * Tt) / BM), 256, 0, stream>>>(
      hsb, WallT, bq, bk, bg, bv, nullptr, qb, kb, lgb, vTb, Bb * Tt, 1024, Hh);

  // 3) fused prep + per-chunk state GEMM
  prep_sgemm_kernel<<<dim3(NC, Bb), 256, 0, stream>>>(qb, kb, lgb, vTb, q2b, qab, kab,
                                                      LBb, Dendb, Sb);

  // 4) sequential chunk recombine -> S0T (pre-chunk states) + final state
  passR_kernel<<<dim3(Vv / 32, Kk / 64, Bb), 256, 0, stream>>>(Sb, Dendb, S0Tb, state_out);

  // 5) outputs: att = q2.S0 + tril(A).v
  passO_kernel<<<dim3(NC, Bb), 256, 0, stream>>>(qab, kab, q2b, LBb, S0Tb, vTb, attb);

  // 6) output projection: pipelined 128^2 kernel, f32 out
  gemm_mf_kernel<1><<<dim3(Oo / BN, (Bb * Tt) / BM), 256, 0, stream>>>(
      attb, WoT, bo, nullptr, nullptr, nullptr, out, nullptr, nullptr, nullptr, nullptr,
      Bb * Tt, Oo, Vv);
}